// Round 1
// baseline (9000.636 us; speedup 1.0000x reference)
//
#include <hip/hip_runtime.h>
#include <hip/hip_bf16.h>
#include <cstddef>

// ---------------- problem constants ----------------
#define BB 2
#define DD 256
#define NH 8
#define NL 4
#define NP 4
#define DFF 1024
#define NLAYERS 6
#define DHD 32
#define Q_TOT 21760
#define NTOK (BB * Q_TOT)   // 43520

// level dims (square): 128,64,32,16 ; starts: 0,16384,20480,21504

// ---------------- init: flatten + transpose (B,D,H,W) -> (B,Q,D) ----------------
__global__ __launch_bounds__(256) void flatten_level(
    const float* __restrict__ src, const float* __restrict__ pos,
    const float* __restrict__ lemb, float* __restrict__ X,
    float* __restrict__ POS, int HW, int start, int lvl) {
  __shared__ float ts[32][33];
  __shared__ float tp[32][33];
  int p0 = blockIdx.x * 32, d0 = blockIdx.y * 32, b = blockIdx.z;
  const float* sb = src + (size_t)b * DD * HW;
  const float* pb = pos + (size_t)b * DD * HW;
  int px = threadIdx.x;
#pragma unroll
  for (int i = 0; i < 4; ++i) {
    int dl = threadIdx.y + i * 8;
    ts[dl][px] = sb[(size_t)(d0 + dl) * HW + p0 + px];
    tp[dl][px] = pb[(size_t)(d0 + dl) * HW + p0 + px];
  }
  __syncthreads();
  int dx = threadIdx.x;
#pragma unroll
  for (int i = 0; i < 4; ++i) {
    int pl = threadIdx.y + i * 8;
    size_t row = (size_t)b * Q_TOT + start + p0 + pl;
    X[row * DD + d0 + dx] = ts[dx][pl];
    POS[row * DD + d0 + dx] = tp[dx][pl] + lemb[lvl * DD + d0 + dx];
  }
}

// ---------------- elementwise add (float4) ----------------
__global__ void add_vec(const float* __restrict__ a, const float* __restrict__ b,
                        float* __restrict__ c, int n4) {
  int i = blockIdx.x * blockDim.x + threadIdx.x;
  if (i < n4) {
    float4 va = ((const float4*)a)[i];
    float4 vb = ((const float4*)b)[i];
    float4 vc = {va.x + vb.x, va.y + vb.y, va.z + vb.z, va.w + vb.w};
    ((float4*)c)[i] = vc;
  }
}

// ---------------- fp32 tiled GEMM: C = A(NxK) * B(KxM) + bias, opt relu ----------------
#define BM 64
#define BN 64
#define BK 16

template <int RELU>
__global__ __launch_bounds__(256) void gemm_bias(
    const float* __restrict__ A, const float* __restrict__ Bw,
    const float* __restrict__ bias, float* __restrict__ C, int K, int M) {
  __shared__ float As[BK][BM + 1];
  __shared__ float Bs[BK][BN];
  int tid = threadIdx.x;
  int row0 = blockIdx.y * BM;
  int col0 = blockIdx.x * BN;
  int ty = tid >> 4, tx = tid & 15;  // 16x16 threads, 4x4 outputs each
  float acc[4][4] = {};
  int ar = tid >> 2;          // 0..63
  int ak = (tid & 3) * 4;     // 0,4,8,12
  int bk = tid >> 4;          // 0..15
  int bc = (tid & 15) * 4;    // 0..60

  for (int k0 = 0; k0 < K; k0 += BK) {
    float4 av = *(const float4*)(A + (size_t)(row0 + ar) * K + k0 + ak);
    As[ak + 0][ar] = av.x;
    As[ak + 1][ar] = av.y;
    As[ak + 2][ar] = av.z;
    As[ak + 3][ar] = av.w;
    *(float4*)&Bs[bk][bc] = *(const float4*)(Bw + (size_t)(k0 + bk) * M + col0 + bc);
    __syncthreads();
#pragma unroll
    for (int k = 0; k < BK; ++k) {
      float a[4], b[4];
#pragma unroll
      for (int i = 0; i < 4; ++i) a[i] = As[k][ty * 4 + i];
#pragma unroll
      for (int j = 0; j < 4; ++j) b[j] = Bs[k][tx * 4 + j];
#pragma unroll
      for (int i = 0; i < 4; ++i)
#pragma unroll
        for (int j = 0; j < 4; ++j) acc[i][j] = fmaf(a[i], b[j], acc[i][j]);
    }
    __syncthreads();
  }
#pragma unroll
  for (int i = 0; i < 4; ++i) {
    int r = row0 + ty * 4 + i;
#pragma unroll
    for (int j = 0; j < 4; ++j) {
      int c = col0 + tx * 4 + j;
      float v = acc[i][j] + bias[c];
      if (RELU) v = fmaxf(v, 0.f);
      C[(size_t)r * M + c] = v;
    }
  }
}

// ---------------- softmax over 16 (level,point) per (token,head) ----------------
__global__ void softmax16(float* __restrict__ AW) {
  int i = blockIdx.x * blockDim.x + threadIdx.x;
  if (i >= NTOK * NH) return;
  float* p = AW + (size_t)(i >> 3) * 128 + (i & 7) * 16;
  float v[16];
  float m = -1e30f;
#pragma unroll
  for (int k = 0; k < 16; ++k) {
    v[k] = p[k];
    m = fmaxf(m, v[k]);
  }
  float s = 0.f;
#pragma unroll
  for (int k = 0; k < 16; ++k) {
    v[k] = expf(v[k] - m);
    s += v[k];
  }
  float r = 1.f / s;
#pragma unroll
  for (int k = 0; k < 16; ++k) p[k] = v[k] * r;
}

// ---------------- deformable bilinear sampling ----------------
// one 32-lane group per (token, head); lane = channel d within head
__global__ __launch_bounds__(256) void sample_ms(
    const float* __restrict__ V, const float* __restrict__ OFF,
    const float* __restrict__ AW, float* __restrict__ SAMP) {
  int g = blockIdx.x * 8 + (threadIdx.x >> 5);
  int lane = threadIdx.x & 31;
  int n = g >> 3;  // token row (b*Q + q)
  int h = g & 7;
  int b = n / Q_TOT;
  int qi = n - b * Q_TOT;
  // this token's own level -> reference point
  int lw = (qi < 16384) ? 7 : (qi < 20480) ? 6 : (qi < 21504) ? 5 : 4;
  int st = (qi < 16384) ? 0 : (qi < 20480) ? 16384 : (qi < 21504) ? 20480 : 21504;
  int wt = 1 << lw;
  int pidx = qi - st;
  int iy = pidx >> lw;
  int ix = pidx & (wt - 1);
  float refx = (ix + 0.5f) / (float)wt;
  float refy = (iy + 0.5f) / (float)wt;

  const float* offp = OFF + (size_t)n * 256 + h * 32;
  const float* awp = AW + (size_t)n * 128 + h * 16;

  constexpr int LW[4] = {128, 64, 32, 16};
  constexpr int LS[4] = {0, 16384, 20480, 21504};

  float acc = 0.f;
#pragma unroll
  for (int l = 0; l < 4; ++l) {
    int wl = LW[l];
    float fw = (float)wl;
    const float* vbase = V + ((size_t)(b * Q_TOT + LS[l])) * 256 + h * 32 + lane;
#pragma unroll
    for (int p = 0; p < 4; ++p) {
      float ox = offp[(l * 4 + p) * 2 + 0];
      float oy = offp[(l * 4 + p) * 2 + 1];
      float a = awp[l * 4 + p];
      float Xc = (refx + ox / fw) * fw - 0.5f;
      float Yc = (refy + oy / fw) * fw - 0.5f;
      float xf = floorf(Xc), yf = floorf(Yc);
      float wx = Xc - xf, wy = Yc - yf;
      int x0 = (int)xf, y0 = (int)yf;
      int x1 = x0 + 1, y1 = y0 + 1;
      bool xin0 = (x0 >= 0) & (x0 < wl), xin1 = (x1 >= 0) & (x1 < wl);
      bool yin0 = (y0 >= 0) & (y0 < wl), yin1 = (y1 >= 0) & (y1 < wl);
      int xc0 = min(max(x0, 0), wl - 1), xc1 = min(max(x1, 0), wl - 1);
      int yc0 = min(max(y0, 0), wl - 1), yc1 = min(max(y1, 0), wl - 1);
      float v00 = 0.f, v10 = 0.f, v01 = 0.f, v11 = 0.f;
      if (xin0 & yin0) v00 = vbase[(size_t)(yc0 * wl + xc0) * 256];
      if (xin1 & yin0) v10 = vbase[(size_t)(yc0 * wl + xc1) * 256];
      if (xin0 & yin1) v01 = vbase[(size_t)(yc1 * wl + xc0) * 256];
      if (xin1 & yin1) v11 = vbase[(size_t)(yc1 * wl + xc1) * 256];
      float s = v00 * (1.f - wx) * (1.f - wy) + v10 * wx * (1.f - wy) +
                v01 * (1.f - wx) * wy + v11 * wx * wy;
      acc = fmaf(a, s, acc);
    }
  }
  SAMP[(size_t)n * 256 + h * 32 + lane] = acc;
}

// ---------------- residual add + LayerNorm (row of 256) ----------------
__global__ __launch_bounds__(256) void add_ln(
    const float* __restrict__ Xin, const float* __restrict__ R,
    const float* __restrict__ g, const float* __restrict__ b,
    float* __restrict__ out) {
  int row = blockIdx.x;
  int d = threadIdx.x;
  float v = Xin[(size_t)row * DD + d] + R[(size_t)row * DD + d];
  float s = v, s2 = v * v;
#pragma unroll
  for (int o = 32; o >= 1; o >>= 1) {
    s += __shfl_xor(s, o);
    s2 += __shfl_xor(s2, o);
  }
  __shared__ float ls[4], ls2[4];
  int wid = threadIdx.x >> 6;
  if ((threadIdx.x & 63) == 0) {
    ls[wid] = s;
    ls2[wid] = s2;
  }
  __syncthreads();
  s = ls[0] + ls[1] + ls[2] + ls[3];
  s2 = ls2[0] + ls2[1] + ls2[2] + ls2[3];
  float m = s * (1.f / 256.f);
  float var = s2 * (1.f / 256.f) - m * m;
  float inv = rsqrtf(var + 1e-5f);
  out[(size_t)row * DD + d] = (v - m) * inv * g[d] + b[d];
}

// ---------------- tail: spatial_shapes + level_start_index (as f32) ----------------
__global__ void write_tail(float* __restrict__ t) {
  int i = threadIdx.x;
  float v = 0.f;
  switch (i) {
    case 0: v = 128.f; break;
    case 1: v = 128.f; break;
    case 2: v = 64.f; break;
    case 3: v = 64.f; break;
    case 4: v = 32.f; break;
    case 5: v = 32.f; break;
    case 6: v = 16.f; break;
    case 7: v = 16.f; break;
    case 8: v = 0.f; break;
    case 9: v = 16384.f; break;
    case 10: v = 20480.f; break;
    case 11: v = 21504.f; break;
    default: return;
  }
  t[i] = v;
}

// ---------------- launch ----------------
extern "C" void kernel_launch(void* const* d_in, const int* in_sizes, int n_in,
                              void* d_out, int out_size, void* d_ws, size_t ws_size,
                              hipStream_t stream) {
  const float* src[4] = {(const float*)d_in[0], (const float*)d_in[2],
                         (const float*)d_in[4], (const float*)d_in[6]};
  const float* pos[4] = {(const float*)d_in[1], (const float*)d_in[3],
                         (const float*)d_in[5], (const float*)d_in[7]};
  const float* lemb = (const float*)d_in[8];
  const float* W_off = (const float*)d_in[9];
  const float* b_off = (const float*)d_in[10];
  const float* W_aw = (const float*)d_in[11];
  const float* b_aw = (const float*)d_in[12];
  const float* W_v = (const float*)d_in[13];
  const float* b_v = (const float*)d_in[14];
  const float* W_out = (const float*)d_in[15];
  const float* b_out = (const float*)d_in[16];
  const float* g1 = (const float*)d_in[17];
  const float* be1 = (const float*)d_in[18];
  const float* W1 = (const float*)d_in[19];
  const float* b1 = (const float*)d_in[20];
  const float* W2 = (const float*)d_in[21];
  const float* b2 = (const float*)d_in[22];
  const float* g2 = (const float*)d_in[23];
  const float* be2 = (const float*)d_in[24];

  float* outx = (float*)d_out;           // x lives in d_out (NTOK*DD floats)
  float* X = outx;
  float* ws = (float*)d_ws;
  float* POS = ws;                        // NTOK*DD
  float* QB = POS + (size_t)NTOK * DD;    // NTOK*DD  (q / attn-out / ffn-out)
  float* SCR = QB + (size_t)NTOK * DD;    // NTOK*DFF scratch
  float* OFF = SCR;                                // NTOK*256
  float* AWb = SCR + (size_t)NTOK * 256;           // NTOK*128
  float* Vb = SCR + (size_t)NTOK * 384;            // NTOK*256
  float* SAMP = SCR + (size_t)NTOK * 640;          // NTOK*256
  float* H1 = SCR;                                 // NTOK*1024 (FFN phase)

  static const int LWh[4] = {128, 64, 32, 16};
  static const int LSh[4] = {0, 16384, 20480, 21504};

  for (int l = 0; l < 4; ++l) {
    int hw = LWh[l] * LWh[l];
    dim3 g(hw / 32, DD / 32, BB);
    flatten_level<<<g, dim3(32, 8), 0, stream>>>(src[l], pos[l], lemb, X, POS,
                                                 hw, LSh[l], l);
  }
  write_tail<<<1, 16, 0, stream>>>(outx + (size_t)NTOK * DD);

  int n4 = NTOK * DD / 4;
  for (int l = 0; l < NLAYERS; ++l) {
    add_vec<<<(n4 + 255) / 256, 256, 0, stream>>>(X, POS, QB, n4);
    gemm_bias<0><<<dim3(256 / BN, NTOK / BM), 256, 0, stream>>>(
        QB, W_off + (size_t)l * DD * 256, b_off + l * 256, OFF, DD, 256);
    gemm_bias<0><<<dim3(128 / BN, NTOK / BM), 256, 0, stream>>>(
        QB, W_aw + (size_t)l * DD * 128, b_aw + l * 128, AWb, DD, 128);
    softmax16<<<(NTOK * NH + 255) / 256, 256, 0, stream>>>(AWb);
    gemm_bias<0><<<dim3(256 / BN, NTOK / BM), 256, 0, stream>>>(
        X, W_v + (size_t)l * DD * 256, b_v + l * 256, Vb, DD, 256);
    sample_ms<<<NTOK * NH / 8, 256, 0, stream>>>(Vb, OFF, AWb, SAMP);
    gemm_bias<0><<<dim3(256 / BN, NTOK / BM), 256, 0, stream>>>(
        SAMP, W_out + (size_t)l * DD * 256, b_out + l * 256, QB, DD, 256);
    add_ln<<<NTOK, 256, 0, stream>>>(X, QB, g1 + l * DD, be1 + l * DD, X);
    gemm_bias<1><<<dim3(DFF / BN, NTOK / BM), 256, 0, stream>>>(
        X, W1 + (size_t)l * DD * DFF, b1 + l * DFF, H1, DD, DFF);
    gemm_bias<0><<<dim3(256 / BN, NTOK / BM), 256, 0, stream>>>(
        H1, W2 + (size_t)l * DFF * 256, b2 + l * 256, QB, DFF, 256);
    add_ln<<<NTOK, 256, 0, stream>>>(X, QB, g2 + l * DD, be2 + l * DD, X);
  }
}

// Round 2
// 2758.345 us; speedup vs baseline: 3.2631x; 3.2631x over previous
//
#include <hip/hip_runtime.h>
#include <cstddef>

// ---------------- problem constants ----------------
#define BB 2
#define DD 256
#define NH 8
#define NL 4
#define NP 4
#define DFF 1024
#define NLAYERS 6
#define Q_TOT 21760
#define NTOK (BB * Q_TOT)   // 43520
#define MTILES (NTOK / 128) // 340

typedef unsigned short ushort_t;
typedef __attribute__((ext_vector_type(8))) short bh8;
typedef __attribute__((ext_vector_type(4))) float fx4;

__device__ __forceinline__ ushort_t f2b(float x) {
  union { float f; unsigned u; } v; v.f = x;
  unsigned r = v.u + 0x7FFF + ((v.u >> 16) & 1);
  return (ushort_t)(r >> 16);
}
__device__ __forceinline__ float b2f(ushort_t b) {
  union { unsigned u; float f; } v; v.u = ((unsigned)b) << 16; return v.f;
}
__device__ __forceinline__ float b2f_hi(unsigned w) {  // high 16 bits as bf16
  union { unsigned u; float f; } v; v.u = w & 0xFFFF0000u; return v.f;
}
__device__ __forceinline__ float b2f_lo(unsigned w) {  // low 16 bits as bf16
  union { unsigned u; float f; } v; v.u = w << 16; return v.f;
}

__device__ __forceinline__ void gload16(const void* g, void* l) {
  __builtin_amdgcn_global_load_lds(
      (const __attribute__((address_space(1))) unsigned int*)g,
      (__attribute__((address_space(3))) unsigned int*)l, 16, 0, 0);
}

// ---------------- init: flatten + transpose (B,D,H,W) -> (B,Q,D) ----------------
__global__ __launch_bounds__(256) void flatten_level(
    const float* __restrict__ src, const float* __restrict__ pos,
    const float* __restrict__ lemb, float* __restrict__ X,
    ushort_t* __restrict__ Xb, ushort_t* __restrict__ POSb,
    int HW, int start, int lvl) {
  __shared__ float ts[32][33];
  __shared__ float tp[32][33];
  int p0 = blockIdx.x * 32, d0 = blockIdx.y * 32, b = blockIdx.z;
  const float* sb = src + (size_t)b * DD * HW;
  const float* pb = pos + (size_t)b * DD * HW;
  int px = threadIdx.x;
#pragma unroll
  for (int i = 0; i < 4; ++i) {
    int dl = threadIdx.y + i * 8;
    ts[dl][px] = sb[(size_t)(d0 + dl) * HW + p0 + px];
    tp[dl][px] = pb[(size_t)(d0 + dl) * HW + p0 + px];
  }
  __syncthreads();
  int dx = threadIdx.x;
#pragma unroll
  for (int i = 0; i < 4; ++i) {
    int pl = threadIdx.y + i * 8;
    size_t row = (size_t)b * Q_TOT + start + p0 + pl;
    float s = ts[dx][pl];
    float p = tp[dx][pl] + lemb[lvl * DD + d0 + dx];
    X[row * DD + d0 + dx] = s;
    Xb[row * DD + d0 + dx] = f2b(s);
    POSb[row * DD + d0 + dx] = f2b(p);
  }
}

// ---------------- weight transpose + bf16: W[K][N] -> WT[N][K] ----------------
__global__ __launch_bounds__(256) void transpose_w(const float* __restrict__ W,
                                                   ushort_t* __restrict__ WT,
                                                   int K, int N) {
  __shared__ float t[32][33];
  int n0 = blockIdx.x * 32, k0 = blockIdx.y * 32, l = blockIdx.z;
  const float* in = W + (size_t)l * K * N;
  ushort_t* out = WT + (size_t)l * K * N;
#pragma unroll
  for (int i = 0; i < 4; ++i) {
    int k = threadIdx.y + i * 8;
    t[k][threadIdx.x] = in[(size_t)(k0 + k) * N + n0 + threadIdx.x];
  }
  __syncthreads();
#pragma unroll
  for (int i = 0; i < 4; ++i) {
    int nn = threadIdx.y + i * 8;
    out[(size_t)(n0 + nn) * K + k0 + threadIdx.x] = f2b(t[threadIdx.x][nn]);
  }
}

// ---------------- q = bf16(X + POS) ----------------
__global__ void add_vec_b(const float* __restrict__ X, const ushort_t* __restrict__ P,
                          ushort_t* __restrict__ Q, int n4) {
  int i = blockIdx.x * 256 + threadIdx.x;
  if (i >= n4) return;
  float4 x = ((const float4*)X)[i];
  ushort4 pb = ((const ushort4*)P)[i];
  ushort4 o;
  o.x = f2b(x.x + b2f(pb.x));
  o.y = f2b(x.y + b2f(pb.y));
  o.z = f2b(x.z + b2f(pb.z));
  o.w = f2b(x.w + b2f(pb.w));
  ((ushort4*)Q)[i] = o;
}

// ---------------- bf16 MFMA GEMM: C[M][N] = A[M][K] * Bt[N][K]^T + bias ----------------
template <int RELU, int OUTBF16>
__global__ __launch_bounds__(256) void gemm_mfma(
    const ushort_t* __restrict__ A, const ushort_t* __restrict__ Bt,
    const float* __restrict__ bias, void* __restrict__ C, int N, int K) {
  __shared__ ushort_t As[128 * 64];
  __shared__ ushort_t Bs[128 * 64];
  int tid = threadIdx.x;
  int m0 = blockIdx.y * 128, n0 = blockIdx.x * 128;
  int wid = tid >> 6, lane = tid & 63;
  int wr = wid >> 1, wc = wid & 1;  // 2x2 wave grid, 64x64 per wave

  fx4 acc[4][4];
#pragma unroll
  for (int i = 0; i < 4; ++i)
#pragma unroll
    for (int j = 0; j < 4; ++j) acc[i][j] = fx4{0.f, 0.f, 0.f, 0.f};

  const ushort_t* ga = A + (size_t)(m0 + (tid >> 3)) * K + (tid & 7) * 8;
  const ushort_t* gb = Bt + (size_t)(n0 + (tid >> 3)) * K + (tid & 7) * 8;
  int ldsbase = wid * 1024;  // byte offset, wave-uniform; HW adds lane*16

  for (int k0 = 0; k0 < K; k0 += 64) {
#pragma unroll
    for (int it = 0; it < 4; ++it) {
      gload16(ga + (size_t)(it * 32) * K + k0, (char*)As + ldsbase + it * 4096);
      gload16(gb + (size_t)(it * 32) * K + k0, (char*)Bs + ldsbase + it * 4096);
    }
    __syncthreads();
#pragma unroll
    for (int kk = 0; kk < 2; ++kk) {
      bh8 af[4], bf[4];
      int cb = kk * 64 + (lane >> 4) * 16;  // byte offset along K
      int ra = wr * 64 + (lane & 15);
      int rb = wc * 64 + (lane & 15);
#pragma unroll
      for (int i = 0; i < 4; ++i)
        af[i] = *(const bh8*)((const char*)As + (ra + i * 16) * 128 + cb);
#pragma unroll
      for (int i = 0; i < 4; ++i)
        bf[i] = *(const bh8*)((const char*)Bs + (rb + i * 16) * 128 + cb);
#pragma unroll
      for (int i = 0; i < 4; ++i)
#pragma unroll
        for (int j = 0; j < 4; ++j)
          acc[i][j] = __builtin_amdgcn_mfma_f32_16x16x32_bf16(af[i], bf[j], acc[i][j], 0, 0, 0);
    }
    __syncthreads();
  }

  int crow = m0 + wr * 64 + (lane >> 4) * 4;
  int ccol = n0 + wc * 64 + (lane & 15);
#pragma unroll
  for (int j = 0; j < 4; ++j) {
    float bv = bias[ccol + j * 16];
#pragma unroll
    for (int i = 0; i < 4; ++i) {
#pragma unroll
      for (int r = 0; r < 4; ++r) {
        float v = acc[i][j][r] + bv;
        if (RELU) v = fmaxf(v, 0.f);
        size_t idx = (size_t)(crow + i * 16 + r) * N + ccol + j * 16;
        if (OUTBF16) ((ushort_t*)C)[idx] = f2b(v);
        else ((float*)C)[idx] = v;
      }
    }
  }
}

// ---------------- softmax over 16 logits per (token,head), bf16 in-place ----------------
__global__ void softmax16b(ushort_t* __restrict__ AW, int ngroups) {
  int i = blockIdx.x * 256 + threadIdx.x;
  if (i >= ngroups) return;
  ushort_t* p = AW + (size_t)i * 16;
  bh8 a = *(const bh8*)p;
  bh8 b = *(const bh8*)(p + 8);
  float v[16];
#pragma unroll
  for (int k = 0; k < 8; ++k) { v[k] = b2f((ushort_t)a[k]); v[k + 8] = b2f((ushort_t)b[k]); }
  float m = v[0];
#pragma unroll
  for (int k = 1; k < 16; ++k) m = fmaxf(m, v[k]);
  float s = 0.f;
#pragma unroll
  for (int k = 0; k < 16; ++k) { v[k] = __expf(v[k] - m); s += v[k]; }
  float r = 1.f / s;
#pragma unroll
  for (int k = 0; k < 8; ++k) { a[k] = (short)f2b(v[k] * r); b[k] = (short)f2b(v[k + 8] * r); }
  *(bh8*)p = a;
  *(bh8*)(p + 8) = b;
}

// ---------------- precompute bilinear meta per (token,head,level,point) ----------------
__global__ void precompute_meta(const ushort_t* __restrict__ OFFb,
                                const ushort_t* __restrict__ AWb,
                                int4* __restrict__ META) {
  int gid = blockIdx.x * 256 + threadIdx.x;
  if (gid >= NTOK * 128) return;
  int p = gid & 3, l = (gid >> 2) & 3, h = (gid >> 4) & 7, t = gid >> 7;
  int b = (t >= Q_TOT) ? 1 : 0;
  int qi = t - b * Q_TOT;
  int lw = (qi < 16384) ? 7 : (qi < 20480) ? 6 : (qi < 21504) ? 5 : 4;
  int st = (qi < 16384) ? 0 : (qi < 20480) ? 16384 : (qi < 21504) ? 20480 : 21504;
  int wt = 1 << lw;
  int pidx = qi - st;
  int iy = pidx >> lw, ix = pidx & (wt - 1);
  float refx = (ix + 0.5f) / (float)wt;
  float refy = (iy + 0.5f) / (float)wt;

  float ox = b2f(OFFb[(size_t)t * 256 + h * 32 + l * 8 + p * 2]);
  float oy = b2f(OFFb[(size_t)t * 256 + h * 32 + l * 8 + p * 2 + 1]);
  float aw = b2f(AWb[(size_t)t * 128 + h * 16 + l * 4 + p]);

  int wl = 128 >> l;
  int LSl = (l > 0 ? 16384 : 0) + (l > 1 ? 4096 : 0) + (l > 2 ? 1024 : 0);
  float fw = (float)wl;
  float Xc = refx * fw + ox - 0.5f;
  float Yc = refy * fw + oy - 0.5f;
  float xf = floorf(Xc), yf = floorf(Yc);
  float wx = Xc - xf, wy = Yc - yf;
  int x0 = (int)xf, y0 = (int)yf;
  int x1 = x0 + 1, y1 = y0 + 1;
  float ok_x0 = (x0 >= 0 && x0 < wl) ? 1.f : 0.f;
  float ok_x1 = (x1 >= 0 && x1 < wl) ? 1.f : 0.f;
  float ok_y0 = (y0 >= 0 && y0 < wl) ? 1.f : 0.f;
  float ok_y1 = (y1 >= 0 && y1 < wl) ? 1.f : 0.f;
  int xc0 = min(max(x0, 0), wl - 1), xc1 = min(max(x1, 0), wl - 1);
  int yc0 = min(max(y0, 0), wl - 1), yc1 = min(max(y1, 0), wl - 1);

  float w00 = (1.f - wx) * (1.f - wy) * aw * ok_x0 * ok_y0;
  float w10 = wx * (1.f - wy) * aw * ok_x1 * ok_y0;
  float w01 = (1.f - wx) * wy * aw * ok_x0 * ok_y1;
  float w11 = wx * wy * aw * ok_x1 * ok_y1;

  int base = ((b * Q_TOT + LSl + yc0 * wl + xc0) << 8) + h * 32;
  unsigned dx = (unsigned)((xc1 - xc0) << 8);        // 0 or 256
  unsigned dy = (unsigned)((yc1 - yc0) * wl) << 8;   // 0 or wl*256 (<=32768)
  int4 m;
  m.x = base;
  m.y = (int)(dx | (dy << 16));
  m.z = (int)(((unsigned)f2b(w00) << 16) | f2b(w10));
  m.w = (int)(((unsigned)f2b(w01) << 16) | f2b(w11));
  META[gid] = m;
}

// ---------------- gather/accumulate sampler ----------------
__global__ __launch_bounds__(256) void sample_v2(const ushort_t* __restrict__ Vb,
                                                 const int4* __restrict__ META,
                                                 ushort_t* __restrict__ SAMPb) {
  int g = blockIdx.x * 8 + (threadIdx.x >> 5);
  int lane = threadIdx.x & 31;
  int n = g >> 3, h = g & 7;
  const int4* mp = META + (size_t)n * 128 + h * 16;
  float acc = 0.f;
#pragma unroll
  for (int p = 0; p < 16; ++p) {
    int4 m = mp[p];
    unsigned dxy = (unsigned)m.y;
    int base = m.x + lane;
    int dx = (int)(dxy & 0xffffu);
    int dy = (int)(dxy >> 16);
    float v00 = b2f(Vb[base]);
    float v10 = b2f(Vb[base + dx]);
    float v01 = b2f(Vb[base + dy]);
    float v11 = b2f(Vb[base + dy + dx]);
    unsigned wz = (unsigned)m.z, ww = (unsigned)m.w;
    acc = fmaf(b2f_hi(wz), v00, acc);
    acc = fmaf(b2f_lo(wz), v10, acc);
    acc = fmaf(b2f_hi(ww), v01, acc);
    acc = fmaf(b2f_lo(ww), v11, acc);
  }
  SAMPb[(size_t)n * 256 + h * 32 + lane] = f2b(acc);
}

// ---------------- residual add + LayerNorm, writes f32 + bf16 ----------------
__global__ __launch_bounds__(256) void add_ln(
    const float* __restrict__ Xin, const float* __restrict__ R,
    const float* __restrict__ g, const float* __restrict__ b,
    float* __restrict__ out, ushort_t* __restrict__ outb) {
  int row = blockIdx.x;
  int d = threadIdx.x;
  float v = Xin[(size_t)row * DD + d] + R[(size_t)row * DD + d];
  float s = v, s2 = v * v;
#pragma unroll
  for (int o = 32; o >= 1; o >>= 1) {
    s += __shfl_xor(s, o);
    s2 += __shfl_xor(s2, o);
  }
  __shared__ float ls[4], ls2[4];
  int wid = threadIdx.x >> 6;
  if ((threadIdx.x & 63) == 0) {
    ls[wid] = s;
    ls2[wid] = s2;
  }
  __syncthreads();
  s = ls[0] + ls[1] + ls[2] + ls[3];
  s2 = ls2[0] + ls2[1] + ls2[2] + ls2[3];
  float m = s * (1.f / 256.f);
  float var = s2 * (1.f / 256.f) - m * m;
  float inv = rsqrtf(var + 1e-5f);
  float y = (v - m) * inv * g[d] + b[d];
  out[(size_t)row * DD + d] = y;
  outb[(size_t)row * DD + d] = f2b(y);
}

// ---------------- tail: spatial_shapes + level_start_index (as f32) ----------------
__global__ void write_tail(float* __restrict__ t) {
  int i = threadIdx.x;
  float v = 0.f;
  switch (i) {
    case 0: v = 128.f; break;
    case 1: v = 128.f; break;
    case 2: v = 64.f; break;
    case 3: v = 64.f; break;
    case 4: v = 32.f; break;
    case 5: v = 32.f; break;
    case 6: v = 16.f; break;
    case 7: v = 16.f; break;
    case 8: v = 0.f; break;
    case 9: v = 16384.f; break;
    case 10: v = 20480.f; break;
    case 11: v = 21504.f; break;
    default: return;
  }
  t[i] = v;
}

// ---------------- launch ----------------
extern "C" void kernel_launch(void* const* d_in, const int* in_sizes, int n_in,
                              void* d_out, int out_size, void* d_ws, size_t ws_size,
                              hipStream_t stream) {
  const float* src[4] = {(const float*)d_in[0], (const float*)d_in[2],
                         (const float*)d_in[4], (const float*)d_in[6]};
  const float* pos[4] = {(const float*)d_in[1], (const float*)d_in[3],
                         (const float*)d_in[5], (const float*)d_in[7]};
  const float* lemb = (const float*)d_in[8];
  const float* W_off = (const float*)d_in[9];
  const float* b_off = (const float*)d_in[10];
  const float* W_aw = (const float*)d_in[11];
  const float* b_aw = (const float*)d_in[12];
  const float* W_v = (const float*)d_in[13];
  const float* b_v = (const float*)d_in[14];
  const float* W_out = (const float*)d_in[15];
  const float* b_out = (const float*)d_in[16];
  const float* g1 = (const float*)d_in[17];
  const float* be1 = (const float*)d_in[18];
  const float* W1 = (const float*)d_in[19];
  const float* b1 = (const float*)d_in[20];
  const float* W2 = (const float*)d_in[21];
  const float* b2 = (const float*)d_in[22];
  const float* g2 = (const float*)d_in[23];
  const float* be2 = (const float*)d_in[24];

  float* X = (float*)d_out;  // residual stream f32 lives in d_out

  // ---- workspace layout (bytes) ----
  char* w = (char*)d_ws;
  const size_t SZ_B = (size_t)NTOK * 256 * 2;  // 22,282,240 bf16 NTOK x 256
  ushort_t* POSb = (ushort_t*)w;               w += SZ_B;
  ushort_t* Xb = (ushort_t*)w;                 w += SZ_B;
  ushort_t* QBb = (ushort_t*)w;                w += SZ_B;
  float* QBf = (float*)w;                      w += (size_t)NTOK * 256 * 4;
  ushort_t* OFFb = (ushort_t*)QBf;                       // alias (dead before QBf written)
  ushort_t* AWb = (ushort_t*)((char*)QBf + SZ_B);        // alias
  ushort_t* Vb = (ushort_t*)w;                 w += SZ_B;
  ushort_t* SAMPb = (ushort_t*)w;              w += SZ_B;
  int4* META = (int4*)w;                       // NTOK*128 int4 = 89,128,960 B
  ushort_t* H1b = (ushort_t*)w;                // alias: NTOK*1024 bf16 = same size
  w += (size_t)NTOK * 128 * 16;
  ushort_t* WTb = (ushort_t*)w;                // 4,521,984 bf16 = 9,043,968 B

  ushort_t* WT_off = WTb;
  ushort_t* WT_aw = WT_off + (size_t)NLAYERS * 256 * 256;
  ushort_t* WT_v = WT_aw + (size_t)NLAYERS * 256 * 128;
  ushort_t* WT_out = WT_v + (size_t)NLAYERS * 256 * 256;
  ushort_t* WT_1 = WT_out + (size_t)NLAYERS * 256 * 256;
  ushort_t* WT_2 = WT_1 + (size_t)NLAYERS * 256 * 1024;

  // ---- weight transposes (per call; cheap) ----
  transpose_w<<<dim3(256 / 32, 256 / 32, NLAYERS), dim3(32, 8), 0, stream>>>(W_off, WT_off, 256, 256);
  transpose_w<<<dim3(128 / 32, 256 / 32, NLAYERS), dim3(32, 8), 0, stream>>>(W_aw, WT_aw, 256, 128);
  transpose_w<<<dim3(256 / 32, 256 / 32, NLAYERS), dim3(32, 8), 0, stream>>>(W_v, WT_v, 256, 256);
  transpose_w<<<dim3(256 / 32, 256 / 32, NLAYERS), dim3(32, 8), 0, stream>>>(W_out, WT_out, 256, 256);
  transpose_w<<<dim3(1024 / 32, 256 / 32, NLAYERS), dim3(32, 8), 0, stream>>>(W1, WT_1, 256, 1024);
  transpose_w<<<dim3(256 / 32, 1024 / 32, NLAYERS), dim3(32, 8), 0, stream>>>(W2, WT_2, 1024, 256);

  static const int LWh[4] = {128, 64, 32, 16};
  static const int LSh[4] = {0, 16384, 20480, 21504};
  for (int l = 0; l < 4; ++l) {
    int hw = LWh[l] * LWh[l];
    dim3 g(hw / 32, DD / 32, BB);
    flatten_level<<<g, dim3(32, 8), 0, stream>>>(src[l], pos[l], lemb, X, Xb, POSb,
                                                 hw, LSh[l], l);
  }
  write_tail<<<1, 16, 0, stream>>>(X + (size_t)NTOK * DD);

  int n4 = NTOK * DD / 4;
  for (int l = 0; l < NLAYERS; ++l) {
    add_vec_b<<<(n4 + 255) / 256, 256, 0, stream>>>(X, POSb, QBb, n4);
    // offsets + attention logits from q
    gemm_mfma<0, 1><<<dim3(2, MTILES), 256, 0, stream>>>(
        QBb, WT_off + (size_t)l * 256 * 256, b_off + l * 256, OFFb, 256, 256);
    gemm_mfma<0, 1><<<dim3(1, MTILES), 256, 0, stream>>>(
        QBb, WT_aw + (size_t)l * 128 * 256, b_aw + l * 128, AWb, 128, 256);
    softmax16b<<<(NTOK * 8 + 255) / 256, 256, 0, stream>>>(AWb, NTOK * 8);
    // values from x
    gemm_mfma<0, 1><<<dim3(2, MTILES), 256, 0, stream>>>(
        Xb, WT_v + (size_t)l * 256 * 256, b_v + l * 256, Vb, 256, 256);
    // bilinear meta + gather
    precompute_meta<<<(NTOK * 128 + 255) / 256, 256, 0, stream>>>(OFFb, AWb, META);
    sample_v2<<<NTOK, 256, 0, stream>>>(Vb, META, SAMPb);
    // output projection -> f32 residual branch
    gemm_mfma<0, 0><<<dim3(2, MTILES), 256, 0, stream>>>(
        SAMPb, WT_out + (size_t)l * 256 * 256, b_out + l * 256, QBf, 256, 256);
    add_ln<<<NTOK, 256, 0, stream>>>(X, QBf, g1 + l * DD, be1 + l * DD, X, Xb);
    // FFN
    gemm_mfma<1, 1><<<dim3(8, MTILES), 256, 0, stream>>>(
        Xb, WT_1 + (size_t)l * 1024 * 256, b1 + l * DFF, H1b, 1024, 256);
    gemm_mfma<0, 0><<<dim3(2, MTILES), 256, 0, stream>>>(
        H1b, WT_2 + (size_t)l * 256 * 1024, b2 + l * 256, QBf, 256, 1024);
    add_ln<<<NTOK, 256, 0, stream>>>(X, QBf, g2 + l * DD, be2 + l * DD, X, Xb);
  }
}

// Round 3
// 2444.969 us; speedup vs baseline: 3.6813x; 1.1282x over previous
//
#include <hip/hip_runtime.h>
#include <cstddef>

// ---------------- problem constants ----------------
#define BB 2
#define DD 256
#define NH 8
#define NL 4
#define NP 4
#define DFF 1024
#define NLAYERS 6
#define Q_TOT 21760
#define NTOK (BB * Q_TOT)   // 43520
#define MTILES (NTOK / 128) // 340

typedef unsigned short ushort_t;
typedef __attribute__((ext_vector_type(8))) short bh8;
typedef __attribute__((ext_vector_type(4))) float fx4;

__device__ __forceinline__ ushort_t f2b(float x) {
  union { float f; unsigned u; } v; v.f = x;
  unsigned r = v.u + 0x7FFF + ((v.u >> 16) & 1);
  return (ushort_t)(r >> 16);
}
__device__ __forceinline__ float b2f(ushort_t b) {
  union { unsigned u; float f; } v; v.u = ((unsigned)b) << 16; return v.f;
}
__device__ __forceinline__ float b2f_hi(unsigned w) {
  union { unsigned u; float f; } v; v.u = w & 0xFFFF0000u; return v.f;
}
__device__ __forceinline__ float b2f_lo(unsigned w) {
  union { unsigned u; float f; } v; v.u = w << 16; return v.f;
}

__device__ __forceinline__ void gload16(const void* g, void* l) {
  __builtin_amdgcn_global_load_lds(
      (const __attribute__((address_space(1))) unsigned int*)g,
      (__attribute__((address_space(3))) unsigned int*)l, 16, 0, 0);
}

// ---------------- init: flatten + transpose (B,D,H,W) -> (B,Q,D) ----------------
__global__ __launch_bounds__(256) void flatten_level(
    const float* __restrict__ src, const float* __restrict__ pos,
    const float* __restrict__ lemb, float* __restrict__ X,
    ushort_t* __restrict__ Xb, ushort_t* __restrict__ POSb,
    int HW, int start, int lvl) {
  __shared__ float ts[32][33];
  __shared__ float tp[32][33];
  int p0 = blockIdx.x * 32, d0 = blockIdx.y * 32, b = blockIdx.z;
  const float* sb = src + (size_t)b * DD * HW;
  const float* pb = pos + (size_t)b * DD * HW;
  int px = threadIdx.x;
#pragma unroll
  for (int i = 0; i < 4; ++i) {
    int dl = threadIdx.y + i * 8;
    ts[dl][px] = sb[(size_t)(d0 + dl) * HW + p0 + px];
    tp[dl][px] = pb[(size_t)(d0 + dl) * HW + p0 + px];
  }
  __syncthreads();
  int dx = threadIdx.x;
#pragma unroll
  for (int i = 0; i < 4; ++i) {
    int pl = threadIdx.y + i * 8;
    size_t row = (size_t)b * Q_TOT + start + p0 + pl;
    float s = ts[dx][pl];
    float p = tp[dx][pl] + lemb[lvl * DD + d0 + dx];
    X[row * DD + d0 + dx] = s;
    Xb[row * DD + d0 + dx] = f2b(s);
    POSb[row * DD + d0 + dx] = f2b(p);
  }
}

// ---------------- weight transpose + bf16: W[K][N] -> WT[rowOff+N][K] ----------------
__global__ __launch_bounds__(256) void transpose_w(const float* __restrict__ W,
                                                   ushort_t* __restrict__ WT,
                                                   int K, int N, int outStride,
                                                   int rowOff) {
  __shared__ float t[32][33];
  int n0 = blockIdx.x * 32, k0 = blockIdx.y * 32, l = blockIdx.z;
  const float* in = W + (size_t)l * K * N;
  ushort_t* out = WT + (size_t)l * outStride;
#pragma unroll
  for (int i = 0; i < 4; ++i) {
    int k = threadIdx.y + i * 8;
    t[k][threadIdx.x] = in[(size_t)(k0 + k) * N + n0 + threadIdx.x];
  }
  __syncthreads();
#pragma unroll
  for (int i = 0; i < 4; ++i) {
    int nn = threadIdx.y + i * 8;
    out[(size_t)(rowOff + n0 + nn) * K + k0 + threadIdx.x] = f2b(t[threadIdx.x][nn]);
  }
}

__global__ void pack_bias(const float* __restrict__ b_off,
                          const float* __restrict__ b_aw,
                          float* __restrict__ b_qa) {
  int l = blockIdx.x, i = threadIdx.x;
  b_qa[l * 384 + i] = (i < 256) ? b_off[l * 256 + i] : b_aw[l * 128 + i - 256];
}

// ---------------- q = bf16(X + POS) ----------------
__global__ void add_vec_b(const float* __restrict__ X, const ushort_t* __restrict__ P,
                          ushort_t* __restrict__ Q, int n4) {
  int i = blockIdx.x * 256 + threadIdx.x;
  if (i >= n4) return;
  float4 x = ((const float4*)X)[i];
  ushort4 pb = ((const ushort4*)P)[i];
  ushort4 o;
  o.x = f2b(x.x + b2f(pb.x));
  o.y = f2b(x.y + b2f(pb.y));
  o.z = f2b(x.z + b2f(pb.z));
  o.w = f2b(x.w + b2f(pb.w));
  ((ushort4*)Q)[i] = o;
}

// ---------------- bf16 MFMA GEMM: C[M][N] = A[M][K] * Bt[N][K]^T + bias ----------------
template <int RELU, int OUTBF16>
__global__ __launch_bounds__(256) void gemm_mfma(
    const ushort_t* __restrict__ A, const ushort_t* __restrict__ Bt,
    const float* __restrict__ bias, void* __restrict__ C, int N, int K) {
  __shared__ ushort_t As[128 * 64];
  __shared__ ushort_t Bs[128 * 64];
  int tid = threadIdx.x;
  int m0 = blockIdx.y * 128, n0 = blockIdx.x * 128;
  int wid = tid >> 6, lane = tid & 63;
  int wr = wid >> 1, wc = wid & 1;

  fx4 acc[4][4];
#pragma unroll
  for (int i = 0; i < 4; ++i)
#pragma unroll
    for (int j = 0; j < 4; ++j) acc[i][j] = fx4{0.f, 0.f, 0.f, 0.f};

  const ushort_t* ga = A + (size_t)(m0 + (tid >> 3)) * K + (tid & 7) * 8;
  const ushort_t* gb = Bt + (size_t)(n0 + (tid >> 3)) * K + (tid & 7) * 8;
  int ldsbase = wid * 1024;

  for (int k0 = 0; k0 < K; k0 += 64) {
#pragma unroll
    for (int it = 0; it < 4; ++it) {
      gload16(ga + (size_t)(it * 32) * K + k0, (char*)As + ldsbase + it * 4096);
      gload16(gb + (size_t)(it * 32) * K + k0, (char*)Bs + ldsbase + it * 4096);
    }
    __syncthreads();
#pragma unroll
    for (int kk = 0; kk < 2; ++kk) {
      bh8 af[4], bf[4];
      int cb = kk * 64 + (lane >> 4) * 16;
      int ra = wr * 64 + (lane & 15);
      int rb = wc * 64 + (lane & 15);
#pragma unroll
      for (int i = 0; i < 4; ++i)
        af[i] = *(const bh8*)((const char*)As + (ra + i * 16) * 128 + cb);
#pragma unroll
      for (int i = 0; i < 4; ++i)
        bf[i] = *(const bh8*)((const char*)Bs + (rb + i * 16) * 128 + cb);
#pragma unroll
      for (int i = 0; i < 4; ++i)
#pragma unroll
        for (int j = 0; j < 4; ++j)
          acc[i][j] = __builtin_amdgcn_mfma_f32_16x16x32_bf16(af[i], bf[j], acc[i][j], 0, 0, 0);
    }
    __syncthreads();
  }

  int crow = m0 + wr * 64 + (lane >> 4) * 4;
  int ccol = n0 + wc * 64 + (lane & 15);
#pragma unroll
  for (int j = 0; j < 4; ++j) {
    float bv = bias[ccol + j * 16];
#pragma unroll
    for (int i = 0; i < 4; ++i) {
#pragma unroll
      for (int r = 0; r < 4; ++r) {
        float v = acc[i][j][r] + bv;
        if (RELU) v = fmaxf(v, 0.f);
        size_t idx = (size_t)(crow + i * 16 + r) * N + ccol + j * 16;
        if (OUTBF16) ((ushort_t*)C)[idx] = f2b(v);
        else ((float*)C)[idx] = v;
      }
    }
  }
}

// ---------------- bf16 MFMA GEMM (N=256) + residual + LayerNorm fused ----------------
__global__ __launch_bounds__(256) void gemm_ln(
    const ushort_t* __restrict__ A, const ushort_t* __restrict__ Bt,
    const float* __restrict__ bias, const float* __restrict__ gamma,
    const float* __restrict__ beta, float* __restrict__ Xf,
    ushort_t* __restrict__ Xb, int K) {
  __shared__ ushort_t As[128 * 64];
  __shared__ ushort_t Bs[256 * 64];
  __shared__ float red[2][2][128];
  int tid = threadIdx.x;
  int m0 = blockIdx.x * 128;
  int wid = tid >> 6, lane = tid & 63;
  int wr = wid >> 1, wc = wid & 1;  // wave covers rows wr*64..+64, cols wc*128..+128

  fx4 acc[4][8];
#pragma unroll
  for (int i = 0; i < 4; ++i)
#pragma unroll
    for (int j = 0; j < 8; ++j) acc[i][j] = fx4{0.f, 0.f, 0.f, 0.f};

  const ushort_t* ga = A + (size_t)(m0 + (tid >> 3)) * K + (tid & 7) * 8;
  const ushort_t* gb = Bt + (size_t)(tid >> 3) * K + (tid & 7) * 8;
  int ldsbase = wid * 1024;

  for (int k0 = 0; k0 < K; k0 += 64) {
#pragma unroll
    for (int it = 0; it < 4; ++it)
      gload16(ga + (size_t)(it * 32) * K + k0, (char*)As + ldsbase + it * 4096);
#pragma unroll
    for (int it = 0; it < 8; ++it)
      gload16(gb + (size_t)(it * 32) * K + k0, (char*)Bs + ldsbase + it * 4096);
    __syncthreads();
#pragma unroll
    for (int kk = 0; kk < 2; ++kk) {
      bh8 af[4], bf[8];
      int cb = kk * 64 + (lane >> 4) * 16;
      int ra = wr * 64 + (lane & 15);
      int rb = wc * 128 + (lane & 15);
#pragma unroll
      for (int i = 0; i < 4; ++i)
        af[i] = *(const bh8*)((const char*)As + (ra + i * 16) * 128 + cb);
#pragma unroll
      for (int j = 0; j < 8; ++j)
        bf[j] = *(const bh8*)((const char*)Bs + (rb + j * 16) * 128 + cb);
#pragma unroll
      for (int i = 0; i < 4; ++i)
#pragma unroll
        for (int j = 0; j < 8; ++j)
          acc[i][j] = __builtin_amdgcn_mfma_f32_16x16x32_bf16(af[i], bf[j], acc[i][j], 0, 0, 0);
    }
    __syncthreads();
  }

  int lg = lane >> 4, lc = lane & 15;
  float bv[8], gv[8], bev[8];
#pragma unroll
  for (int j = 0; j < 8; ++j) {
    int col = wc * 128 + j * 16 + lc;
    bv[j] = bias[col];
    gv[j] = gamma[col];
    bev[j] = beta[col];
  }
  // pass 1: v = acc + bias + residual; per-row sum/sumsq
#pragma unroll
  for (int i = 0; i < 4; ++i) {
#pragma unroll
    for (int r = 0; r < 4; ++r) {
      int rloc = wr * 64 + i * 16 + lg * 4 + r;
      const float* xr = Xf + (size_t)(m0 + rloc) * DD + wc * 128 + lc;
      float s = 0.f, s2 = 0.f;
#pragma unroll
      for (int j = 0; j < 8; ++j) {
        float v = acc[i][j][r] + bv[j] + xr[j * 16];
        acc[i][j][r] = v;
        s += v;
        s2 += v * v;
      }
#pragma unroll
      for (int o = 1; o < 16; o <<= 1) {
        s += __shfl_xor(s, o);
        s2 += __shfl_xor(s2, o);
      }
      if (lc == 0) {
        red[wc][0][rloc] = s;
        red[wc][1][rloc] = s2;
      }
    }
  }
  __syncthreads();
  // pass 2: normalize + write f32 and bf16
#pragma unroll
  for (int i = 0; i < 4; ++i) {
#pragma unroll
    for (int r = 0; r < 4; ++r) {
      int rloc = wr * 64 + i * 16 + lg * 4 + r;
      float s = red[0][0][rloc] + red[1][0][rloc];
      float s2 = red[0][1][rloc] + red[1][1][rloc];
      float mmean = s * (1.f / 256.f);
      float var = s2 * (1.f / 256.f) - mmean * mmean;
      float inv = rsqrtf(var + 1e-5f);
      size_t rowb = (size_t)(m0 + rloc) * DD + wc * 128 + lc;
#pragma unroll
      for (int j = 0; j < 8; ++j) {
        float y = (acc[i][j][r] - mmean) * inv * gv[j] + bev[j];
        Xf[rowb + j * 16] = y;
        Xb[rowb + j * 16] = f2b(y);
      }
    }
  }
}

// ---------------- softmax + bilinear meta per (token,head) ----------------
__global__ void meta_softmax(const ushort_t* __restrict__ QA,
                             int4* __restrict__ META) {
  int gid = blockIdx.x * 256 + threadIdx.x;
  if (gid >= NTOK * 8) return;
  int t = gid >> 3, h = gid & 7;
  int b = (t >= Q_TOT) ? 1 : 0;
  int qi = t - b * Q_TOT;
  int lw = (qi < 16384) ? 7 : (qi < 20480) ? 6 : (qi < 21504) ? 5 : 4;
  int st = (qi < 16384) ? 0 : (qi < 20480) ? 16384 : (qi < 21504) ? 20480 : 21504;
  int wt = 1 << lw;
  int pidx = qi - st;
  int iy = pidx >> lw, ix = pidx & (wt - 1);
  float refx = (ix + 0.5f) / (float)wt;
  float refy = (iy + 0.5f) / (float)wt;

  // softmax over 16 logits
  const ushort_t* lp = QA + (size_t)t * 384 + 256 + h * 16;
  bh8 la = *(const bh8*)lp;
  bh8 lb = *(const bh8*)(lp + 8);
  float aw[16];
#pragma unroll
  for (int k = 0; k < 8; ++k) {
    aw[k] = b2f((ushort_t)la[k]);
    aw[k + 8] = b2f((ushort_t)lb[k]);
  }
  float mx = aw[0];
#pragma unroll
  for (int k = 1; k < 16; ++k) mx = fmaxf(mx, aw[k]);
  float sum = 0.f;
#pragma unroll
  for (int k = 0; k < 16; ++k) {
    aw[k] = __expf(aw[k] - mx);
    sum += aw[k];
  }
  float rs = 1.f / sum;

  const ushort_t* op = QA + (size_t)t * 384 + h * 32;
  int4* mo = META + (size_t)gid * 16;
#pragma unroll
  for (int l = 0; l < 4; ++l) {
    bh8 ov = *(const bh8*)(op + l * 8);
    int wl = 128 >> l;
    int LSl = (l > 0 ? 16384 : 0) + (l > 1 ? 4096 : 0) + (l > 2 ? 1024 : 0);
    float fw = (float)wl;
#pragma unroll
    for (int p = 0; p < 4; ++p) {
      float ox = b2f((ushort_t)ov[p * 2]);
      float oy = b2f((ushort_t)ov[p * 2 + 1]);
      float a = aw[l * 4 + p] * rs;
      float Xc = refx * fw + ox - 0.5f;
      float Yc = refy * fw + oy - 0.5f;
      float xf = floorf(Xc), yf = floorf(Yc);
      float wx = Xc - xf, wy = Yc - yf;
      int x0 = (int)xf, y0 = (int)yf;
      int x1 = x0 + 1, y1 = y0 + 1;
      float ok_x0 = (x0 >= 0 && x0 < wl) ? 1.f : 0.f;
      float ok_x1 = (x1 >= 0 && x1 < wl) ? 1.f : 0.f;
      float ok_y0 = (y0 >= 0 && y0 < wl) ? 1.f : 0.f;
      float ok_y1 = (y1 >= 0 && y1 < wl) ? 1.f : 0.f;
      int xc0 = min(max(x0, 0), wl - 1), xc1 = min(max(x1, 0), wl - 1);
      int yc0 = min(max(y0, 0), wl - 1), yc1 = min(max(y1, 0), wl - 1);
      float w00 = (1.f - wx) * (1.f - wy) * a * ok_x0 * ok_y0;
      float w10 = wx * (1.f - wy) * a * ok_x1 * ok_y0;
      float w01 = (1.f - wx) * wy * a * ok_x0 * ok_y1;
      float w11 = wx * wy * a * ok_x1 * ok_y1;
      int base = ((b * Q_TOT + LSl + yc0 * wl + xc0) << 8) + h * 32;
      unsigned dx = (unsigned)((xc1 - xc0) << 8);
      unsigned dy = (unsigned)((yc1 - yc0) * wl) << 8;
      int4 m;
      m.x = base;
      m.y = (int)(dx | (dy << 16));
      m.z = (int)(((unsigned)f2b(w00) << 16) | f2b(w10));
      m.w = (int)(((unsigned)f2b(w01) << 16) | f2b(w11));
      mo[l * 4 + p] = m;
    }
  }
}

// ---------------- gather/accumulate sampler: 16 lanes per (t,h), ushort2 loads ----
__global__ __launch_bounds__(256) void sample_v3(const ushort_t* __restrict__ Vb,
                                                 const int4* __restrict__ META,
                                                 ushort_t* __restrict__ SAMPb) {
  // XCD-chunked swizzle over blocks (NTOK/2 blocks, %8==0)
  int nb = NTOK / 2;
  int bid = blockIdx.x;
  int newb = (bid & 7) * (nb >> 3) + (bid >> 3);
  int t = newb * 2 + (threadIdx.x >> 7);
  int h = (threadIdx.x >> 4) & 7;
  int lc = threadIdx.x & 15;
  int c2 = lc * 2;

  const int4* mp = META + ((size_t)t * 8 + h) * 16;
  int4 mreg[16];
#pragma unroll
  for (int p = 0; p < 16; ++p) mreg[p] = mp[p];

  float acc0 = 0.f, acc1 = 0.f;
#pragma unroll
  for (int p = 0; p < 16; ++p) {
    int4 m = mreg[p];
    unsigned dxy = (unsigned)m.y;
    int base = m.x + c2;
    int dx = (int)(dxy & 0xffffu);
    int dy = (int)(dxy >> 16);
    unsigned v00 = *(const unsigned*)(Vb + base);
    unsigned v10 = *(const unsigned*)(Vb + base + dx);
    unsigned v01 = *(const unsigned*)(Vb + base + dy);
    unsigned v11 = *(const unsigned*)(Vb + base + dy + dx);
    unsigned wz = (unsigned)m.z, ww = (unsigned)m.w;
    float w00 = b2f_hi(wz), w10 = b2f_lo(wz);
    float w01 = b2f_hi(ww), w11 = b2f_lo(ww);
    acc0 = fmaf(w00, b2f_lo(v00), acc0);
    acc1 = fmaf(w00, b2f_hi(v00), acc1);
    acc0 = fmaf(w10, b2f_lo(v10), acc0);
    acc1 = fmaf(w10, b2f_hi(v10), acc1);
    acc0 = fmaf(w01, b2f_lo(v01), acc0);
    acc1 = fmaf(w01, b2f_hi(v01), acc1);
    acc0 = fmaf(w11, b2f_lo(v11), acc0);
    acc1 = fmaf(w11, b2f_hi(v11), acc1);
  }
  unsigned outw = (unsigned)f2b(acc0) | ((unsigned)f2b(acc1) << 16);
  *(unsigned*)(SAMPb + (size_t)t * 256 + h * 32 + c2) = outw;
}

// ---------------- tail: spatial_shapes + level_start_index (as f32) ----------------
__global__ void write_tail(float* __restrict__ t) {
  int i = threadIdx.x;
  float v = 0.f;
  switch (i) {
    case 0: v = 128.f; break;
    case 1: v = 128.f; break;
    case 2: v = 64.f; break;
    case 3: v = 64.f; break;
    case 4: v = 32.f; break;
    case 5: v = 32.f; break;
    case 6: v = 16.f; break;
    case 7: v = 16.f; break;
    case 8: v = 0.f; break;
    case 9: v = 16384.f; break;
    case 10: v = 20480.f; break;
    case 11: v = 21504.f; break;
    default: return;
  }
  t[i] = v;
}

// ---------------- launch ----------------
extern "C" void kernel_launch(void* const* d_in, const int* in_sizes, int n_in,
                              void* d_out, int out_size, void* d_ws, size_t ws_size,
                              hipStream_t stream) {
  const float* src[4] = {(const float*)d_in[0], (const float*)d_in[2],
                         (const float*)d_in[4], (const float*)d_in[6]};
  const float* pos[4] = {(const float*)d_in[1], (const float*)d_in[3],
                         (const float*)d_in[5], (const float*)d_in[7]};
  const float* lemb = (const float*)d_in[8];
  const float* W_off = (const float*)d_in[9];
  const float* b_off = (const float*)d_in[10];
  const float* W_aw = (const float*)d_in[11];
  const float* b_aw = (const float*)d_in[12];
  const float* W_v = (const float*)d_in[13];
  const float* b_v = (const float*)d_in[14];
  const float* W_out = (const float*)d_in[15];
  const float* b_out = (const float*)d_in[16];
  const float* g1 = (const float*)d_in[17];
  const float* be1 = (const float*)d_in[18];
  const float* W1 = (const float*)d_in[19];
  const float* b1 = (const float*)d_in[20];
  const float* W2 = (const float*)d_in[21];
  const float* b2 = (const float*)d_in[22];
  const float* g2 = (const float*)d_in[23];
  const float* be2 = (const float*)d_in[24];

  float* X = (float*)d_out;  // f32 residual stream lives in d_out

  // ---- workspace layout ----
  char* w = (char*)d_ws;
  const size_t SZ_B = (size_t)NTOK * 256 * 2;
  ushort_t* POSb = (ushort_t*)w;  w += SZ_B;
  ushort_t* Xb = (ushort_t*)w;    w += SZ_B;
  ushort_t* QBb = (ushort_t*)w;   w += SZ_B;
  ushort_t* QAb = (ushort_t*)w;   w += (size_t)NTOK * 384 * 2;
  ushort_t* Vb = (ushort_t*)w;    w += SZ_B;
  ushort_t* SAMPb = (ushort_t*)w; w += SZ_B;
  int4* META = (int4*)w;                 // NTOK*128*16 B
  ushort_t* H1b = (ushort_t*)w;          // alias (disjoint lifetime)
  w += (size_t)NTOK * 128 * 16;
  ushort_t* WT_qa = (ushort_t*)w;  w += (size_t)NLAYERS * 384 * 256 * 2;
  ushort_t* WT_v = (ushort_t*)w;   w += (size_t)NLAYERS * 256 * 256 * 2;
  ushort_t* WT_out = (ushort_t*)w; w += (size_t)NLAYERS * 256 * 256 * 2;
  ushort_t* WT_1 = (ushort_t*)w;   w += (size_t)NLAYERS * 1024 * 256 * 2;
  ushort_t* WT_2 = (ushort_t*)w;   w += (size_t)NLAYERS * 256 * 1024 * 2;
  float* b_qa = (float*)w;         w += (size_t)NLAYERS * 384 * 4;

  // ---- weight prep ----
  transpose_w<<<dim3(8, 8, NLAYERS), dim3(32, 8), 0, stream>>>(W_off, WT_qa, 256, 256, 384 * 256, 0);
  transpose_w<<<dim3(4, 8, NLAYERS), dim3(32, 8), 0, stream>>>(W_aw, WT_qa, 256, 128, 384 * 256, 256);
  pack_bias<<<NLAYERS, 384, 0, stream>>>(b_off, b_aw, b_qa);
  transpose_w<<<dim3(8, 8, NLAYERS), dim3(32, 8), 0, stream>>>(W_v, WT_v, 256, 256, 256 * 256, 0);
  transpose_w<<<dim3(8, 8, NLAYERS), dim3(32, 8), 0, stream>>>(W_out, WT_out, 256, 256, 256 * 256, 0);
  transpose_w<<<dim3(32, 8, NLAYERS), dim3(32, 8), 0, stream>>>(W1, WT_1, 256, 1024, 1024 * 256, 0);
  transpose_w<<<dim3(8, 32, NLAYERS), dim3(32, 8), 0, stream>>>(W2, WT_2, 1024, 256, 256 * 1024, 0);

  static const int LWh[4] = {128, 64, 32, 16};
  static const int LSh[4] = {0, 16384, 20480, 21504};
  for (int l = 0; l < 4; ++l) {
    int hw = LWh[l] * LWh[l];
    dim3 g(hw / 32, DD / 32, BB);
    flatten_level<<<g, dim3(32, 8), 0, stream>>>(src[l], pos[l], lemb, X, Xb, POSb,
                                                 hw, LSh[l], l);
  }
  write_tail<<<1, 16, 0, stream>>>(X + (size_t)NTOK * DD);

  int n4 = NTOK * DD / 4;
  for (int l = 0; l < NLAYERS; ++l) {
    add_vec_b<<<(n4 + 255) / 256, 256, 0, stream>>>(X, POSb, QBb, n4);
    // fused offsets+logits GEMM (N=384)
    gemm_mfma<0, 1><<<dim3(3, MTILES), 256, 0, stream>>>(
        QBb, WT_qa + (size_t)l * 384 * 256, b_qa + l * 384, QAb, 384, 256);
    meta_softmax<<<(NTOK * 8 + 255) / 256, 256, 0, stream>>>(QAb, META);
    // values
    gemm_mfma<0, 1><<<dim3(2, MTILES), 256, 0, stream>>>(
        Xb, WT_v + (size_t)l * 256 * 256, b_v + l * 256, Vb, 256, 256);
    sample_v3<<<NTOK / 2, 256, 0, stream>>>(Vb, META, SAMPb);
    // out projection + residual + LN1 (fused)
    gemm_ln<<<MTILES, 256, 0, stream>>>(
        SAMPb, WT_out + (size_t)l * 256 * 256, b_out + l * 256,
        g1 + l * DD, be1 + l * DD, X, Xb, 256);
    // FFN
    gemm_mfma<1, 1><<<dim3(8, MTILES), 256, 0, stream>>>(
        Xb, WT_1 + (size_t)l * 1024 * 256, b1 + l * DFF, H1b, 1024, 256);
    gemm_ln<<<MTILES, 256, 0, stream>>>(
        H1b, WT_2 + (size_t)l * 256 * 1024, b2 + l * 256,
        g2 + l * DD, be2 + l * DD, X, Xb, 1024);
  }
}

// Round 4
// 1966.078 us; speedup vs baseline: 4.5780x; 1.2436x over previous
//
#include <hip/hip_runtime.h>
#include <cstddef>

// ---------------- problem constants ----------------
#define BB 2
#define DD 256
#define NH 8
#define NL 4
#define NP 4
#define DFF 1024
#define NLAYERS 6
#define Q_TOT 21760
#define NTOK (BB * Q_TOT)   // 43520
#define MTILES (NTOK / 128) // 340
#define LTILES (NTOK / 64)  // 680

typedef unsigned short ushort_t;
typedef __attribute__((ext_vector_type(8))) short bh8;
typedef __attribute__((ext_vector_type(4))) float fx4;

__device__ __forceinline__ ushort_t f2b(float x) {
  union { float f; unsigned u; } v; v.f = x;
  unsigned r = v.u + 0x7FFF + ((v.u >> 16) & 1);
  return (ushort_t)(r >> 16);
}
__device__ __forceinline__ float b2f(ushort_t b) {
  union { unsigned u; float f; } v; v.u = ((unsigned)b) << 16; return v.f;
}
__device__ __forceinline__ float b2f_hi(unsigned w) {
  union { unsigned u; float f; } v; v.u = w & 0xFFFF0000u; return v.f;
}
__device__ __forceinline__ float b2f_lo(unsigned w) {
  union { unsigned u; float f; } v; v.u = w << 16; return v.f;
}

__device__ __forceinline__ void gload16(const void* g, void* l) {
  __builtin_amdgcn_global_load_lds(
      (const __attribute__((address_space(1))) unsigned int*)g,
      (__attribute__((address_space(3))) unsigned int*)l, 16, 0, 0);
}

// ---------------- init: flatten + transpose (B,D,H,W) -> (B,Q,D) ----------------
__global__ __launch_bounds__(256) void flatten_level(
    const float* __restrict__ src, const float* __restrict__ pos,
    const float* __restrict__ lemb, float* __restrict__ X,
    ushort_t* __restrict__ Xb, ushort_t* __restrict__ POSb,
    ushort_t* __restrict__ QBb, int HW, int start, int lvl) {
  __shared__ float ts[32][33];
  __shared__ float tp[32][33];
  int p0 = blockIdx.x * 32, d0 = blockIdx.y * 32, b = blockIdx.z;
  const float* sb = src + (size_t)b * DD * HW;
  const float* pb = pos + (size_t)b * DD * HW;
  int px = threadIdx.x;
#pragma unroll
  for (int i = 0; i < 4; ++i) {
    int dl = threadIdx.y + i * 8;
    ts[dl][px] = sb[(size_t)(d0 + dl) * HW + p0 + px];
    tp[dl][px] = pb[(size_t)(d0 + dl) * HW + p0 + px];
  }
  __syncthreads();
  int dx = threadIdx.x;
#pragma unroll
  for (int i = 0; i < 4; ++i) {
    int pl = threadIdx.y + i * 8;
    size_t row = (size_t)b * Q_TOT + start + p0 + pl;
    float s = ts[dx][pl];
    float p = tp[dx][pl] + lemb[lvl * DD + d0 + dx];
    X[row * DD + d0 + dx] = s;
    Xb[row * DD + d0 + dx] = f2b(s);
    POSb[row * DD + d0 + dx] = f2b(p);
    QBb[row * DD + d0 + dx] = f2b(s + p);
  }
}

// ---------------- weight transpose + bf16: W[K][N] -> WT[rowOff+N][K] ----------------
__global__ __launch_bounds__(256) void transpose_w(const float* __restrict__ W,
                                                   ushort_t* __restrict__ WT,
                                                   int K, int N, int outStride,
                                                   int rowOff) {
  __shared__ float t[32][33];
  int n0 = blockIdx.x * 32, k0 = blockIdx.y * 32, l = blockIdx.z;
  const float* in = W + (size_t)l * K * N;
  ushort_t* out = WT + (size_t)l * outStride;
#pragma unroll
  for (int i = 0; i < 4; ++i) {
    int k = threadIdx.y + i * 8;
    t[k][threadIdx.x] = in[(size_t)(k0 + k) * N + n0 + threadIdx.x];
  }
  __syncthreads();
#pragma unroll
  for (int i = 0; i < 4; ++i) {
    int nn = threadIdx.y + i * 8;
    out[(size_t)(rowOff + n0 + nn) * K + k0 + threadIdx.x] = f2b(t[threadIdx.x][nn]);
  }
}

__global__ void pack_bias(const float* __restrict__ b_off,
                          const float* __restrict__ b_aw,
                          float* __restrict__ b_qa) {
  int l = blockIdx.x, i = threadIdx.x;
  b_qa[l * 384 + i] = (i < 256) ? b_off[l * 256 + i] : b_aw[l * 128 + i - 256];
}

// ---------------- bf16 MFMA GEMM (128x128 tile): C = A * Bt^T + bias ----------------
template <int RELU, int OUTBF16>
__global__ __launch_bounds__(256) void gemm_mfma(
    const ushort_t* __restrict__ A, const ushort_t* __restrict__ Bt,
    const float* __restrict__ bias, void* __restrict__ C, int N, int K) {
  __shared__ ushort_t As[128 * 64];
  __shared__ ushort_t Bs[128 * 64];
  int tid = threadIdx.x;
  int m0 = blockIdx.y * 128, n0 = blockIdx.x * 128;
  int wid = tid >> 6, lane = tid & 63;
  int wr = wid >> 1, wc = wid & 1;

  fx4 acc[4][4];
#pragma unroll
  for (int i = 0; i < 4; ++i)
#pragma unroll
    for (int j = 0; j < 4; ++j) acc[i][j] = fx4{0.f, 0.f, 0.f, 0.f};

  const ushort_t* ga = A + (size_t)(m0 + (tid >> 3)) * K + (tid & 7) * 8;
  const ushort_t* gb = Bt + (size_t)(n0 + (tid >> 3)) * K + (tid & 7) * 8;
  int ldsbase = wid * 1024;

  for (int k0 = 0; k0 < K; k0 += 64) {
#pragma unroll
    for (int it = 0; it < 4; ++it) {
      gload16(ga + (size_t)(it * 32) * K + k0, (char*)As + ldsbase + it * 4096);
      gload16(gb + (size_t)(it * 32) * K + k0, (char*)Bs + ldsbase + it * 4096);
    }
    __syncthreads();
#pragma unroll
    for (int kk = 0; kk < 2; ++kk) {
      bh8 af[4], bf[4];
      int cb = kk * 64 + (lane >> 4) * 16;
      int ra = wr * 64 + (lane & 15);
      int rb = wc * 64 + (lane & 15);
#pragma unroll
      for (int i = 0; i < 4; ++i)
        af[i] = *(const bh8*)((const char*)As + (ra + i * 16) * 128 + cb);
#pragma unroll
      for (int i = 0; i < 4; ++i)
        bf[i] = *(const bh8*)((const char*)Bs + (rb + i * 16) * 128 + cb);
#pragma unroll
      for (int i = 0; i < 4; ++i)
#pragma unroll
        for (int j = 0; j < 4; ++j)
          acc[i][j] = __builtin_amdgcn_mfma_f32_16x16x32_bf16(af[i], bf[j], acc[i][j], 0, 0, 0);
    }
    __syncthreads();
  }

  int crow = m0 + wr * 64 + (lane >> 4) * 4;
  int ccol = n0 + wc * 64 + (lane & 15);
#pragma unroll
  for (int j = 0; j < 4; ++j) {
    float bv = bias[ccol + j * 16];
#pragma unroll
    for (int i = 0; i < 4; ++i) {
#pragma unroll
      for (int r = 0; r < 4; ++r) {
        float v = acc[i][j][r] + bv;
        if (RELU) v = fmaxf(v, 0.f);
        size_t idx = (size_t)(crow + i * 16 + r) * N + ccol + j * 16;
        if (OUTBF16) ((ushort_t*)C)[idx] = f2b(v);
        else ((float*)C)[idx] = v;
      }
    }
  }
}

// ---- bf16 MFMA GEMM (64x256 tile) + residual + LayerNorm (+ optional q-out) ----
template <int QOUT>
__global__ __launch_bounds__(256) void gemm_ln(
    const ushort_t* __restrict__ A, const ushort_t* __restrict__ Bt,
    const float* __restrict__ bias, const float* __restrict__ gamma,
    const float* __restrict__ beta, float* __restrict__ Xf,
    ushort_t* __restrict__ Xb, const ushort_t* __restrict__ POSb,
    ushort_t* __restrict__ QBb, int K) {
  __shared__ ushort_t As[64 * 64];
  __shared__ ushort_t Bs[256 * 64];
  __shared__ float red[2][2][64];
  int tid = threadIdx.x;
  int m0 = blockIdx.x * 64;
  int wid = tid >> 6, lane = tid & 63;
  int wr = wid >> 1, wc = wid & 1;  // wave: rows wr*32..+32, cols wc*128..+128

  fx4 acc[2][8];
#pragma unroll
  for (int i = 0; i < 2; ++i)
#pragma unroll
    for (int j = 0; j < 8; ++j) acc[i][j] = fx4{0.f, 0.f, 0.f, 0.f};

  const ushort_t* ga = A + (size_t)(m0 + (tid >> 3)) * K + (tid & 7) * 8;
  const ushort_t* gb = Bt + (size_t)(tid >> 3) * K + (tid & 7) * 8;
  int ldsbase = wid * 1024;

  for (int k0 = 0; k0 < K; k0 += 64) {
#pragma unroll
    for (int it = 0; it < 2; ++it)
      gload16(ga + (size_t)(it * 32) * K + k0, (char*)As + ldsbase + it * 4096);
#pragma unroll
    for (int it = 0; it < 8; ++it)
      gload16(gb + (size_t)(it * 32) * K + k0, (char*)Bs + ldsbase + it * 4096);
    __syncthreads();
#pragma unroll
    for (int kk = 0; kk < 2; ++kk) {
      bh8 af[2], bf[8];
      int cb = kk * 64 + (lane >> 4) * 16;
      int ra = wr * 32 + (lane & 15);
      int rb = wc * 128 + (lane & 15);
#pragma unroll
      for (int i = 0; i < 2; ++i)
        af[i] = *(const bh8*)((const char*)As + (ra + i * 16) * 128 + cb);
#pragma unroll
      for (int j = 0; j < 8; ++j)
        bf[j] = *(const bh8*)((const char*)Bs + (rb + j * 16) * 128 + cb);
#pragma unroll
      for (int i = 0; i < 2; ++i)
#pragma unroll
        for (int j = 0; j < 8; ++j)
          acc[i][j] = __builtin_amdgcn_mfma_f32_16x16x32_bf16(af[i], bf[j], acc[i][j], 0, 0, 0);
    }
    __syncthreads();
  }

  int lg = lane >> 4, lc = lane & 15;
  float bv[8], gv[8], bev[8];
#pragma unroll
  for (int j = 0; j < 8; ++j) {
    int col = wc * 128 + j * 16 + lc;
    bv[j] = bias[col];
    gv[j] = gamma[col];
    bev[j] = beta[col];
  }
  // pass 1: v = acc + bias + residual; per-row sum/sumsq
#pragma unroll
  for (int i = 0; i < 2; ++i) {
#pragma unroll
    for (int r = 0; r < 4; ++r) {
      int rloc = wr * 32 + i * 16 + lg * 4 + r;
      const float* xr = Xf + (size_t)(m0 + rloc) * DD + wc * 128 + lc;
      float s = 0.f, s2 = 0.f;
#pragma unroll
      for (int j = 0; j < 8; ++j) {
        float v = acc[i][j][r] + bv[j] + xr[j * 16];
        acc[i][j][r] = v;
        s += v;
        s2 += v * v;
      }
#pragma unroll
      for (int o = 1; o < 16; o <<= 1) {
        s += __shfl_xor(s, o);
        s2 += __shfl_xor(s2, o);
      }
      if (lc == 0) {
        red[wc][0][rloc] = s;
        red[wc][1][rloc] = s2;
      }
    }
  }
  __syncthreads();
  // pass 2: normalize + write f32 / bf16 / optional q = bf16(y + pos)
#pragma unroll
  for (int i = 0; i < 2; ++i) {
#pragma unroll
    for (int r = 0; r < 4; ++r) {
      int rloc = wr * 32 + i * 16 + lg * 4 + r;
      float s = red[0][0][rloc] + red[1][0][rloc];
      float s2 = red[0][1][rloc] + red[1][1][rloc];
      float mmean = s * (1.f / 256.f);
      float var = s2 * (1.f / 256.f) - mmean * mmean;
      float inv = rsqrtf(var + 1e-5f);
      size_t rowb = (size_t)(m0 + rloc) * DD + wc * 128 + lc;
#pragma unroll
      for (int j = 0; j < 8; ++j) {
        float y = (acc[i][j][r] - mmean) * inv * gv[j] + bev[j];
        Xf[rowb + j * 16] = y;
        Xb[rowb + j * 16] = f2b(y);
        if (QOUT) QBb[rowb + j * 16] = f2b(y + b2f(POSb[rowb + j * 16]));
      }
    }
  }
}

// ---------------- fused softmax + meta + gather sampler ----------------
// 16 lanes per (token,head): lane p owns point p's meta; gather loop
// broadcasts metas via shfl; each lane gathers channel pair 2p..2p+1.
__global__ __launch_bounds__(256) void sample_v4(const ushort_t* __restrict__ Vb,
                                                 const ushort_t* __restrict__ QA,
                                                 ushort_t* __restrict__ SAMPb) {
  int nb = NTOK / 2;
  int bid = blockIdx.x;
  int newb = (bid & 7) * (nb >> 3) + (bid >> 3);  // XCD-chunked swizzle
  int t = newb * 2 + (threadIdx.x >> 7);
  int h = (threadIdx.x >> 4) & 7;
  int p = threadIdx.x & 15;

  int b = (t >= Q_TOT) ? 1 : 0;
  int qi = t - b * Q_TOT;
  int lwq = (qi < 16384) ? 7 : (qi < 20480) ? 6 : (qi < 21504) ? 5 : 4;
  int stq = (qi < 16384) ? 0 : (qi < 20480) ? 16384 : (qi < 21504) ? 20480 : 21504;
  int wt = 1 << lwq;
  int pidx = qi - stq;
  int iy = pidx >> lwq, ix = pidx & (wt - 1);
  float refx = (ix + 0.5f) / (float)wt;
  float refy = (iy + 0.5f) / (float)wt;

  // softmax over the 16 points (one logit per lane)
  float lgt = b2f(QA[(size_t)t * 384 + 256 + h * 16 + p]);
  float mxv = lgt;
#pragma unroll
  for (int o = 1; o < 16; o <<= 1) mxv = fmaxf(mxv, __shfl_xor(mxv, o, 16));
  float e = __expf(lgt - mxv);
  float sum = e;
#pragma unroll
  for (int o = 1; o < 16; o <<= 1) sum += __shfl_xor(sum, o, 16);
  float a = e / sum;

  // bilinear meta for point p = (level l, point pt)
  int l = p >> 2, pt = p & 3;
  int wl = 128 >> l;
  int LSl = (l > 0 ? 16384 : 0) + (l > 1 ? 4096 : 0) + (l > 2 ? 1024 : 0);
  float fw = (float)wl;
  unsigned ow = *(const unsigned*)(QA + (size_t)t * 384 + h * 32 + l * 8 + pt * 2);
  float ox = b2f_lo(ow), oy = b2f_hi(ow);
  float Xc = refx * fw + ox - 0.5f;
  float Yc = refy * fw + oy - 0.5f;
  float xf = floorf(Xc), yf = floorf(Yc);
  float wx = Xc - xf, wy = Yc - yf;
  int x0 = (int)xf, y0 = (int)yf;
  int x1 = x0 + 1, y1 = y0 + 1;
  float ok_x0 = (x0 >= 0 && x0 < wl) ? 1.f : 0.f;
  float ok_x1 = (x1 >= 0 && x1 < wl) ? 1.f : 0.f;
  float ok_y0 = (y0 >= 0 && y0 < wl) ? 1.f : 0.f;
  float ok_y1 = (y1 >= 0 && y1 < wl) ? 1.f : 0.f;
  int xc0 = min(max(x0, 0), wl - 1), xc1 = min(max(x1, 0), wl - 1);
  int yc0 = min(max(y0, 0), wl - 1), yc1 = min(max(y1, 0), wl - 1);
  float w00 = (1.f - wx) * (1.f - wy) * a * ok_x0 * ok_y0;
  float w10 = wx * (1.f - wy) * a * ok_x1 * ok_y0;
  float w01 = (1.f - wx) * wy * a * ok_x0 * ok_y1;
  float w11 = wx * wy * a * ok_x1 * ok_y1;
  int metaBase = ((b * Q_TOT + LSl + yc0 * wl + xc0) << 8) + h * 32;
  int metaDxy = (int)(((unsigned)((xc1 - xc0) << 8)) |
                      (((unsigned)((yc1 - yc0) * wl) << 8) << 16));
  int metaZ = (int)(((unsigned)f2b(w00) << 16) | f2b(w10));
  int metaW = (int)(((unsigned)f2b(w01) << 16) | f2b(w11));

  int c2 = p * 2;  // this lane's channel pair within the head
  float acc0 = 0.f, acc1 = 0.f;
#pragma unroll
  for (int pp = 0; pp < 16; ++pp) {
    int m0v = __shfl(metaBase, pp, 16);
    int m1v = __shfl(metaDxy, pp, 16);
    int mzv = __shfl(metaZ, pp, 16);
    int mwv = __shfl(metaW, pp, 16);
    unsigned dxy = (unsigned)m1v;
    int base = m0v + c2;
    int dx = (int)(dxy & 0xffffu);
    int dy = (int)(dxy >> 16);
    unsigned v00 = *(const unsigned*)(Vb + base);
    unsigned v10 = *(const unsigned*)(Vb + base + dx);
    unsigned v01 = *(const unsigned*)(Vb + base + dy);
    unsigned v11 = *(const unsigned*)(Vb + base + dy + dx);
    unsigned wz = (unsigned)mzv, ww = (unsigned)mwv;
    float f00 = b2f_hi(wz), f10 = b2f_lo(wz);
    float f01 = b2f_hi(ww), f11 = b2f_lo(ww);
    acc0 = fmaf(f00, b2f_lo(v00), acc0);
    acc1 = fmaf(f00, b2f_hi(v00), acc1);
    acc0 = fmaf(f10, b2f_lo(v10), acc0);
    acc1 = fmaf(f10, b2f_hi(v10), acc1);
    acc0 = fmaf(f01, b2f_lo(v01), acc0);
    acc1 = fmaf(f01, b2f_hi(v01), acc1);
    acc0 = fmaf(f11, b2f_lo(v11), acc0);
    acc1 = fmaf(f11, b2f_hi(v11), acc1);
  }
  unsigned outw = (unsigned)f2b(acc0) | ((unsigned)f2b(acc1) << 16);
  *(unsigned*)(SAMPb + (size_t)t * 256 + h * 32 + c2) = outw;
}

// ---------------- tail: spatial_shapes + level_start_index (as f32) ----------------
__global__ void write_tail(float* __restrict__ t) {
  int i = threadIdx.x;
  float v = 0.f;
  switch (i) {
    case 0: v = 128.f; break;
    case 1: v = 128.f; break;
    case 2: v = 64.f; break;
    case 3: v = 64.f; break;
    case 4: v = 32.f; break;
    case 5: v = 32.f; break;
    case 6: v = 16.f; break;
    case 7: v = 16.f; break;
    case 8: v = 0.f; break;
    case 9: v = 16384.f; break;
    case 10: v = 20480.f; break;
    case 11: v = 21504.f; break;
    default: return;
  }
  t[i] = v;
}

// ---------------- launch ----------------
extern "C" void kernel_launch(void* const* d_in, const int* in_sizes, int n_in,
                              void* d_out, int out_size, void* d_ws, size_t ws_size,
                              hipStream_t stream) {
  const float* src[4] = {(const float*)d_in[0], (const float*)d_in[2],
                         (const float*)d_in[4], (const float*)d_in[6]};
  const float* pos[4] = {(const float*)d_in[1], (const float*)d_in[3],
                         (const float*)d_in[5], (const float*)d_in[7]};
  const float* lemb = (const float*)d_in[8];
  const float* W_off = (const float*)d_in[9];
  const float* b_off = (const float*)d_in[10];
  const float* W_aw = (const float*)d_in[11];
  const float* b_aw = (const float*)d_in[12];
  const float* W_v = (const float*)d_in[13];
  const float* b_v = (const float*)d_in[14];
  const float* W_out = (const float*)d_in[15];
  const float* b_out = (const float*)d_in[16];
  const float* g1 = (const float*)d_in[17];
  const float* be1 = (const float*)d_in[18];
  const float* W1 = (const float*)d_in[19];
  const float* b1 = (const float*)d_in[20];
  const float* W2 = (const float*)d_in[21];
  const float* b2 = (const float*)d_in[22];
  const float* g2 = (const float*)d_in[23];
  const float* be2 = (const float*)d_in[24];

  float* X = (float*)d_out;  // f32 residual stream lives in d_out

  // ---- workspace layout ----
  char* w = (char*)d_ws;
  const size_t SZ_B = (size_t)NTOK * 256 * 2;
  ushort_t* POSb = (ushort_t*)w;  w += SZ_B;
  ushort_t* Xb = (ushort_t*)w;    w += SZ_B;
  ushort_t* QBb = (ushort_t*)w;   w += SZ_B;
  ushort_t* QAb = (ushort_t*)w;   w += (size_t)NTOK * 384 * 2;
  ushort_t* Vb = (ushort_t*)w;    w += SZ_B;
  ushort_t* SAMPb = (ushort_t*)w; w += SZ_B;
  ushort_t* H1b = (ushort_t*)w;   w += (size_t)NTOK * DFF * 2;
  ushort_t* WT_qa = (ushort_t*)w;  w += (size_t)NLAYERS * 384 * 256 * 2;
  ushort_t* WT_v = (ushort_t*)w;   w += (size_t)NLAYERS * 256 * 256 * 2;
  ushort_t* WT_out = (ushort_t*)w; w += (size_t)NLAYERS * 256 * 256 * 2;
  ushort_t* WT_1 = (ushort_t*)w;   w += (size_t)NLAYERS * 1024 * 256 * 2;
  ushort_t* WT_2 = (ushort_t*)w;   w += (size_t)NLAYERS * 256 * 1024 * 2;
  float* b_qa = (float*)w;         w += (size_t)NLAYERS * 384 * 4;

  // ---- weight prep ----
  transpose_w<<<dim3(8, 8, NLAYERS), dim3(32, 8), 0, stream>>>(W_off, WT_qa, 256, 256, 384 * 256, 0);
  transpose_w<<<dim3(4, 8, NLAYERS), dim3(32, 8), 0, stream>>>(W_aw, WT_qa, 256, 128, 384 * 256, 256);
  pack_bias<<<NLAYERS, 384, 0, stream>>>(b_off, b_aw, b_qa);
  transpose_w<<<dim3(8, 8, NLAYERS), dim3(32, 8), 0, stream>>>(W_v, WT_v, 256, 256, 256 * 256, 0);
  transpose_w<<<dim3(8, 8, NLAYERS), dim3(32, 8), 0, stream>>>(W_out, WT_out, 256, 256, 256 * 256, 0);
  transpose_w<<<dim3(32, 8, NLAYERS), dim3(32, 8), 0, stream>>>(W1, WT_1, 256, 1024, 1024 * 256, 0);
  transpose_w<<<dim3(8, 32, NLAYERS), dim3(32, 8), 0, stream>>>(W2, WT_2, 1024, 256, 256 * 1024, 0);

  static const int LWh[4] = {128, 64, 32, 16};
  static const int LSh[4] = {0, 16384, 20480, 21504};
  for (int l = 0; l < 4; ++l) {
    int hw = LWh[l] * LWh[l];
    dim3 g(hw / 32, DD / 32, BB);
    flatten_level<<<g, dim3(32, 8), 0, stream>>>(src[l], pos[l], lemb, X, Xb, POSb,
                                                 QBb, hw, LSh[l], l);
  }
  write_tail<<<1, 16, 0, stream>>>(X + (size_t)NTOK * DD);

  for (int l = 0; l < NLAYERS; ++l) {
    // fused offsets+logits GEMM (N=384) from q
    gemm_mfma<0, 1><<<dim3(3, MTILES), 256, 0, stream>>>(
        QBb, WT_qa + (size_t)l * 384 * 256, b_qa + l * 384, QAb, 384, 256);
    // values from x
    gemm_mfma<0, 1><<<dim3(2, MTILES), 256, 0, stream>>>(
        Xb, WT_v + (size_t)l * 256 * 256, b_v + l * 256, Vb, 256, 256);
    // fused softmax + meta + gather
    sample_v4<<<NTOK / 2, 256, 0, stream>>>(Vb, QAb, SAMPb);
    // out projection + residual + LN1
    gemm_ln<0><<<LTILES, 256, 0, stream>>>(
        SAMPb, WT_out + (size_t)l * 256 * 256, b_out + l * 256,
        g1 + l * DD, be1 + l * DD, X, Xb, POSb, QBb, 256);
    // FFN
    gemm_mfma<1, 1><<<dim3(8, MTILES), 256, 0, stream>>>(
        Xb, WT_1 + (size_t)l * 1024 * 256, b1 + l * DFF, H1b, 1024, 256);
    gemm_ln<1><<<LTILES, 256, 0, stream>>>(
        H1b, WT_2 + (size_t)l * 256 * 1024, b2 + l * 256,
        g2 + l * DD, be2 + l * DD, X, Xb, POSb, QBb, 1024);
  }
}

// Round 5
// 1961.042 us; speedup vs baseline: 4.5897x; 1.0026x over previous
//
#include <hip/hip_runtime.h>
#include <cstddef>

// ---------------- problem constants ----------------
#define BB 2
#define DD 256
#define NH 8
#define NL 4
#define NP 4
#define DFF 1024
#define NLAYERS 6
#define Q_TOT 21760
#define NTOK (BB * Q_TOT)   // 43520
#define MTILES (NTOK / 128) // 340
#define LTILES (NTOK / 64)  // 680

typedef unsigned short ushort_t;
typedef __attribute__((ext_vector_type(8))) short bh8;
typedef __attribute__((ext_vector_type(4))) float fx4;

__device__ __forceinline__ ushort_t f2b(float x) {
  union { float f; unsigned u; } v; v.f = x;
  unsigned r = v.u + 0x7FFF + ((v.u >> 16) & 1);
  return (ushort_t)(r >> 16);
}
__device__ __forceinline__ float b2f(ushort_t b) {
  union { unsigned u; float f; } v; v.u = ((unsigned)b) << 16; return v.f;
}
__device__ __forceinline__ float b2f_hi(unsigned w) {
  union { unsigned u; float f; } v; v.u = w & 0xFFFF0000u; return v.f;
}
__device__ __forceinline__ float b2f_lo(unsigned w) {
  union { unsigned u; float f; } v; v.u = w << 16; return v.f;
}

__device__ __forceinline__ void gload16(const void* g, void* l) {
  __builtin_amdgcn_global_load_lds(
      (const __attribute__((address_space(1))) unsigned int*)g,
      (__attribute__((address_space(3))) unsigned int*)l, 16, 0, 0);
}

// ---------------- init: flatten + transpose (B,D,H,W) -> (B,Q,D) ----------------
__global__ __launch_bounds__(256) void flatten_level(
    const float* __restrict__ src, const float* __restrict__ pos,
    const float* __restrict__ lemb, float* __restrict__ X,
    ushort_t* __restrict__ Xb, ushort_t* __restrict__ POSb,
    ushort_t* __restrict__ QBb, int HW, int start, int lvl) {
  __shared__ float ts[32][33];
  __shared__ float tp[32][33];
  int p0 = blockIdx.x * 32, d0 = blockIdx.y * 32, b = blockIdx.z;
  const float* sb = src + (size_t)b * DD * HW;
  const float* pb = pos + (size_t)b * DD * HW;
  int px = threadIdx.x;
#pragma unroll
  for (int i = 0; i < 4; ++i) {
    int dl = threadIdx.y + i * 8;
    ts[dl][px] = sb[(size_t)(d0 + dl) * HW + p0 + px];
    tp[dl][px] = pb[(size_t)(d0 + dl) * HW + p0 + px];
  }
  __syncthreads();
  int dx = threadIdx.x;
#pragma unroll
  for (int i = 0; i < 4; ++i) {
    int pl = threadIdx.y + i * 8;
    size_t row = (size_t)b * Q_TOT + start + p0 + pl;
    float s = ts[dx][pl];
    float p = tp[dx][pl] + lemb[lvl * DD + d0 + dx];
    X[row * DD + d0 + dx] = s;
    Xb[row * DD + d0 + dx] = f2b(s);
    POSb[row * DD + d0 + dx] = f2b(p);
    QBb[row * DD + d0 + dx] = f2b(s + p);
  }
}

// ---------------- weight transpose + bf16: W[K][N] -> WT[rowOff+N][K] ----------------
__global__ __launch_bounds__(256) void transpose_w(const float* __restrict__ W,
                                                   ushort_t* __restrict__ WT,
                                                   int K, int N, int outStride,
                                                   int rowOff) {
  __shared__ float t[32][33];
  int n0 = blockIdx.x * 32, k0 = blockIdx.y * 32, l = blockIdx.z;
  const float* in = W + (size_t)l * K * N;
  ushort_t* out = WT + (size_t)l * outStride;
#pragma unroll
  for (int i = 0; i < 4; ++i) {
    int k = threadIdx.y + i * 8;
    t[k][threadIdx.x] = in[(size_t)(k0 + k) * N + n0 + threadIdx.x];
  }
  __syncthreads();
#pragma unroll
  for (int i = 0; i < 4; ++i) {
    int nn = threadIdx.y + i * 8;
    out[(size_t)(rowOff + n0 + nn) * K + k0 + threadIdx.x] = f2b(t[threadIdx.x][nn]);
  }
}

__global__ void pack_bias(const float* __restrict__ b_off,
                          const float* __restrict__ b_aw,
                          float* __restrict__ b_qa) {
  int l = blockIdx.x, i = threadIdx.x;
  b_qa[l * 384 + i] = (i < 256) ? b_off[l * 256 + i] : b_aw[l * 128 + i - 256];
}

// ---------------- bf16 MFMA GEMM (128x128 tile): C = A * Bt^T + bias ----------------
template <int RELU, int OUTBF16>
__global__ __launch_bounds__(256) void gemm_mfma(
    const ushort_t* __restrict__ A, const ushort_t* __restrict__ Bt,
    const float* __restrict__ bias, void* __restrict__ C, int N, int K) {
  __shared__ ushort_t As[128 * 64];
  __shared__ ushort_t Bs[128 * 64];
  int tid = threadIdx.x;
  int m0 = blockIdx.y * 128, n0 = blockIdx.x * 128;
  int wid = tid >> 6, lane = tid & 63;
  int wr = wid >> 1, wc = wid & 1;

  fx4 acc[4][4];
#pragma unroll
  for (int i = 0; i < 4; ++i)
#pragma unroll
    for (int j = 0; j < 4; ++j) acc[i][j] = fx4{0.f, 0.f, 0.f, 0.f};

  const ushort_t* ga = A + (size_t)(m0 + (tid >> 3)) * K + (tid & 7) * 8;
  const ushort_t* gb = Bt + (size_t)(n0 + (tid >> 3)) * K + (tid & 7) * 8;
  int ldsbase = wid * 1024;

  for (int k0 = 0; k0 < K; k0 += 64) {
#pragma unroll
    for (int it = 0; it < 4; ++it) {
      gload16(ga + (size_t)(it * 32) * K + k0, (char*)As + ldsbase + it * 4096);
      gload16(gb + (size_t)(it * 32) * K + k0, (char*)Bs + ldsbase + it * 4096);
    }
    __syncthreads();
#pragma unroll
    for (int kk = 0; kk < 2; ++kk) {
      bh8 af[4], bf[4];
      int cb = kk * 64 + (lane >> 4) * 16;
      int ra = wr * 64 + (lane & 15);
      int rb = wc * 64 + (lane & 15);
#pragma unroll
      for (int i = 0; i < 4; ++i)
        af[i] = *(const bh8*)((const char*)As + (ra + i * 16) * 128 + cb);
#pragma unroll
      for (int i = 0; i < 4; ++i)
        bf[i] = *(const bh8*)((const char*)Bs + (rb + i * 16) * 128 + cb);
#pragma unroll
      for (int i = 0; i < 4; ++i)
#pragma unroll
        for (int j = 0; j < 4; ++j)
          acc[i][j] = __builtin_amdgcn_mfma_f32_16x16x32_bf16(af[i], bf[j], acc[i][j], 0, 0, 0);
    }
    __syncthreads();
  }

  int crow = m0 + wr * 64 + (lane >> 4) * 4;
  int ccol = n0 + wc * 64 + (lane & 15);
#pragma unroll
  for (int j = 0; j < 4; ++j) {
    float bv = bias[ccol + j * 16];
#pragma unroll
    for (int i = 0; i < 4; ++i) {
#pragma unroll
      for (int r = 0; r < 4; ++r) {
        float v = acc[i][j][r] + bv;
        if (RELU) v = fmaxf(v, 0.f);
        size_t idx = (size_t)(crow + i * 16 + r) * N + ccol + j * 16;
        if (OUTBF16) ((ushort_t*)C)[idx] = f2b(v);
        else ((float*)C)[idx] = v;
      }
    }
  }
}

// ---- bf16 MFMA GEMM (64x256 tile, BK=32, XOR-swizzled LDS) + residual + LN ----
// LDS swizzle: 16B slot' = slot ^ ((row>>1)&3), 64B rows. global_load_lds writes
// linearly, so the global SOURCE is pre-swizzled (same involution) and ds_reads
// XOR the slot; spreads each 16-lane group's rows across all 8 bank groups.
template <int QOUT>
__global__ __launch_bounds__(256) void gemm_ln(
    const ushort_t* __restrict__ A, const ushort_t* __restrict__ Bt,
    const float* __restrict__ bias, const float* __restrict__ gamma,
    const float* __restrict__ beta, float* __restrict__ Xf,
    ushort_t* __restrict__ Xb, const ushort_t* __restrict__ POSb,
    ushort_t* __restrict__ QBb, int K) {
  __shared__ ushort_t As[64 * 32];
  __shared__ ushort_t Bs[256 * 32];
  __shared__ float red[2][2][64];
  int tid = threadIdx.x;
  int m0 = blockIdx.x * 64;
  int wid = tid >> 6, lane = tid & 63;
  int wr = wid >> 1, wc = wid & 1;  // wave: rows wr*32..+32, cols wc*128..+128

  fx4 acc[2][8];
#pragma unroll
  for (int i = 0; i < 2; ++i)
#pragma unroll
    for (int j = 0; j < 8; ++j) acc[i][j] = fx4{0.f, 0.f, 0.f, 0.f};

  // staging: thread t -> LDS row t>>2 (64B rows), slot t&3; global slot
  // pre-swizzled by ((row>>1)&3) = (t>>3)&3.
  int srow = tid >> 2;
  int sslot = (tid & 3) ^ ((tid >> 3) & 3);
  const ushort_t* ga = A + (size_t)(m0 + srow) * K + sslot * 8;
  const ushort_t* gb = Bt + (size_t)srow * K + sslot * 8;
  int ldsbase = wid * 1024;

  // read-side swizzled column byte offset (lane-only)
  int cbyte = (((lane >> 4) ^ ((lane >> 1) & 3)) << 4);
  int ra = wr * 32 + (lane & 15);
  int rb = wc * 128 + (lane & 15);

  for (int k0 = 0; k0 < K; k0 += 32) {
    gload16(ga + k0, (char*)As + ldsbase);
#pragma unroll
    for (int it = 0; it < 4; ++it)
      gload16(gb + (size_t)(it * 64) * K + k0, (char*)Bs + it * 4096 + ldsbase);
    __syncthreads();
    bh8 af[2], bf[8];
#pragma unroll
    for (int i = 0; i < 2; ++i)
      af[i] = *(const bh8*)((const char*)As + (ra + i * 16) * 64 + cbyte);
#pragma unroll
    for (int j = 0; j < 8; ++j)
      bf[j] = *(const bh8*)((const char*)Bs + (rb + j * 16) * 64 + cbyte);
#pragma unroll
    for (int i = 0; i < 2; ++i)
#pragma unroll
      for (int j = 0; j < 8; ++j)
        acc[i][j] = __builtin_amdgcn_mfma_f32_16x16x32_bf16(af[i], bf[j], acc[i][j], 0, 0, 0);
    __syncthreads();
  }

  int lg = lane >> 4, lc = lane & 15;
  float bv[8], gv[8], bev[8];
#pragma unroll
  for (int j = 0; j < 8; ++j) {
    int col = wc * 128 + j * 16 + lc;
    bv[j] = bias[col];
    gv[j] = gamma[col];
    bev[j] = beta[col];
  }
  // pass 1: v = acc + bias + residual; per-row sum/sumsq
#pragma unroll
  for (int i = 0; i < 2; ++i) {
#pragma unroll
    for (int r = 0; r < 4; ++r) {
      int rloc = wr * 32 + i * 16 + lg * 4 + r;
      const float* xr = Xf + (size_t)(m0 + rloc) * DD + wc * 128 + lc;
      float s = 0.f, s2 = 0.f;
#pragma unroll
      for (int j = 0; j < 8; ++j) {
        float v = acc[i][j][r] + bv[j] + xr[j * 16];
        acc[i][j][r] = v;
        s += v;
        s2 += v * v;
      }
#pragma unroll
      for (int o = 1; o < 16; o <<= 1) {
        s += __shfl_xor(s, o);
        s2 += __shfl_xor(s2, o);
      }
      if (lc == 0) {
        red[wc][0][rloc] = s;
        red[wc][1][rloc] = s2;
      }
    }
  }
  __syncthreads();
  // pass 2: normalize + write f32 / bf16 / optional q = bf16(y + pos)
#pragma unroll
  for (int i = 0; i < 2; ++i) {
#pragma unroll
    for (int r = 0; r < 4; ++r) {
      int rloc = wr * 32 + i * 16 + lg * 4 + r;
      float s = red[0][0][rloc] + red[1][0][rloc];
      float s2 = red[0][1][rloc] + red[1][1][rloc];
      float mmean = s * (1.f / 256.f);
      float var = s2 * (1.f / 256.f) - mmean * mmean;
      float inv = rsqrtf(var + 1e-5f);
      size_t rowb = (size_t)(m0 + rloc) * DD + wc * 128 + lc;
#pragma unroll
      for (int j = 0; j < 8; ++j) {
        float y = (acc[i][j][r] - mmean) * inv * gv[j] + bev[j];
        Xf[rowb + j * 16] = y;
        Xb[rowb + j * 16] = f2b(y);
        if (QOUT) QBb[rowb + j * 16] = f2b(y + b2f(POSb[rowb + j * 16]));
      }
    }
  }
}

// ---------------- fused softmax + meta + gather sampler ----------------
__global__ __launch_bounds__(256) void sample_v4(const ushort_t* __restrict__ Vb,
                                                 const ushort_t* __restrict__ QA,
                                                 ushort_t* __restrict__ SAMPb) {
  int nb = NTOK / 2;
  int bid = blockIdx.x;
  int newb = (bid & 7) * (nb >> 3) + (bid >> 3);  // XCD-chunked swizzle
  int t = newb * 2 + (threadIdx.x >> 7);
  int h = (threadIdx.x >> 4) & 7;
  int p = threadIdx.x & 15;

  int b = (t >= Q_TOT) ? 1 : 0;
  int qi = t - b * Q_TOT;
  int lwq = (qi < 16384) ? 7 : (qi < 20480) ? 6 : (qi < 21504) ? 5 : 4;
  int stq = (qi < 16384) ? 0 : (qi < 20480) ? 16384 : (qi < 21504) ? 20480 : 21504;
  int wt = 1 << lwq;
  int pidx = qi - stq;
  int iy = pidx >> lwq, ix = pidx & (wt - 1);
  float refx = (ix + 0.5f) / (float)wt;
  float refy = (iy + 0.5f) / (float)wt;

  // softmax over the 16 points (one logit per lane)
  float lgt = b2f(QA[(size_t)t * 384 + 256 + h * 16 + p]);
  float mxv = lgt;
#pragma unroll
  for (int o = 1; o < 16; o <<= 1) mxv = fmaxf(mxv, __shfl_xor(mxv, o, 16));
  float e = __expf(lgt - mxv);
  float sum = e;
#pragma unroll
  for (int o = 1; o < 16; o <<= 1) sum += __shfl_xor(sum, o, 16);
  float a = e / sum;

  // bilinear meta for point p = (level l, point pt)
  int l = p >> 2, pt = p & 3;
  int wl = 128 >> l;
  int LSl = (l > 0 ? 16384 : 0) + (l > 1 ? 4096 : 0) + (l > 2 ? 1024 : 0);
  float fw = (float)wl;
  unsigned ow = *(const unsigned*)(QA + (size_t)t * 384 + h * 32 + l * 8 + pt * 2);
  float ox = b2f_lo(ow), oy = b2f_hi(ow);
  float Xc = refx * fw + ox - 0.5f;
  float Yc = refy * fw + oy - 0.5f;
  float xf = floorf(Xc), yf = floorf(Yc);
  float wx = Xc - xf, wy = Yc - yf;
  int x0 = (int)xf, y0 = (int)yf;
  int x1 = x0 + 1, y1 = y0 + 1;
  float ok_x0 = (x0 >= 0 && x0 < wl) ? 1.f : 0.f;
  float ok_x1 = (x1 >= 0 && x1 < wl) ? 1.f : 0.f;
  float ok_y0 = (y0 >= 0 && y0 < wl) ? 1.f : 0.f;
  float ok_y1 = (y1 >= 0 && y1 < wl) ? 1.f : 0.f;
  int xc0 = min(max(x0, 0), wl - 1), xc1 = min(max(x1, 0), wl - 1);
  int yc0 = min(max(y0, 0), wl - 1), yc1 = min(max(y1, 0), wl - 1);
  float w00 = (1.f - wx) * (1.f - wy) * a * ok_x0 * ok_y0;
  float w10 = wx * (1.f - wy) * a * ok_x1 * ok_y0;
  float w01 = (1.f - wx) * wy * a * ok_x0 * ok_y1;
  float w11 = wx * wy * a * ok_x1 * ok_y1;
  int metaBase = ((b * Q_TOT + LSl + yc0 * wl + xc0) << 8) + h * 32;
  int metaDxy = (int)(((unsigned)((xc1 - xc0) << 8)) |
                      (((unsigned)((yc1 - yc0) * wl) << 8) << 16));
  int metaZ = (int)(((unsigned)f2b(w00) << 16) | f2b(w10));
  int metaW = (int)(((unsigned)f2b(w01) << 16) | f2b(w11));

  int c2 = p * 2;  // this lane's channel pair within the head
  float acc0 = 0.f, acc1 = 0.f;
#pragma unroll
  for (int pp = 0; pp < 16; ++pp) {
    int m0v = __shfl(metaBase, pp, 16);
    int m1v = __shfl(metaDxy, pp, 16);
    int mzv = __shfl(metaZ, pp, 16);
    int mwv = __shfl(metaW, pp, 16);
    unsigned dxy = (unsigned)m1v;
    int base = m0v + c2;
    int dx = (int)(dxy & 0xffffu);
    int dy = (int)(dxy >> 16);
    unsigned v00 = *(const unsigned*)(Vb + base);
    unsigned v10 = *(const unsigned*)(Vb + base + dx);
    unsigned v01 = *(const unsigned*)(Vb + base + dy);
    unsigned v11 = *(const unsigned*)(Vb + base + dy + dx);
    unsigned wz = (unsigned)mzv, ww = (unsigned)mwv;
    float f00 = b2f_hi(wz), f10 = b2f_lo(wz);
    float f01 = b2f_hi(ww), f11 = b2f_lo(ww);
    acc0 = fmaf(f00, b2f_lo(v00), acc0);
    acc1 = fmaf(f00, b2f_hi(v00), acc1);
    acc0 = fmaf(f10, b2f_lo(v10), acc0);
    acc1 = fmaf(f10, b2f_hi(v10), acc1);
    acc0 = fmaf(f01, b2f_lo(v01), acc0);
    acc1 = fmaf(f01, b2f_hi(v01), acc1);
    acc0 = fmaf(f11, b2f_lo(v11), acc0);
    acc1 = fmaf(f11, b2f_hi(v11), acc1);
  }
  unsigned outw = (unsigned)f2b(acc0) | ((unsigned)f2b(acc1) << 16);
  *(unsigned*)(SAMPb + (size_t)t * 256 + h * 32 + c2) = outw;
}

// ---------------- tail: spatial_shapes + level_start_index (as f32) ----------------
__global__ void write_tail(float* __restrict__ t) {
  int i = threadIdx.x;
  float v = 0.f;
  switch (i) {
    case 0: v = 128.f; break;
    case 1: v = 128.f; break;
    case 2: v = 64.f; break;
    case 3: v = 64.f; break;
    case 4: v = 32.f; break;
    case 5: v = 32.f; break;
    case 6: v = 16.f; break;
    case 7: v = 16.f; break;
    case 8: v = 0.f; break;
    case 9: v = 16384.f; break;
    case 10: v = 20480.f; break;
    case 11: v = 21504.f; break;
    default: return;
  }
  t[i] = v;
}

// ---------------- launch ----------------
extern "C" void kernel_launch(void* const* d_in, const int* in_sizes, int n_in,
                              void* d_out, int out_size, void* d_ws, size_t ws_size,
                              hipStream_t stream) {
  const float* src[4] = {(const float*)d_in[0], (const float*)d_in[2],
                         (const float*)d_in[4], (const float*)d_in[6]};
  const float* pos[4] = {(const float*)d_in[1], (const float*)d_in[3],
                         (const float*)d_in[5], (const float*)d_in[7]};
  const float* lemb = (const float*)d_in[8];
  const float* W_off = (const float*)d_in[9];
  const float* b_off = (const float*)d_in[10];
  const float* W_aw = (const float*)d_in[11];
  const float* b_aw = (const float*)d_in[12];
  const float* W_v = (const float*)d_in[13];
  const float* b_v = (const float*)d_in[14];
  const float* W_out = (const float*)d_in[15];
  const float* b_out = (const float*)d_in[16];
  const float* g1 = (const float*)d_in[17];
  const float* be1 = (const float*)d_in[18];
  const float* W1 = (const float*)d_in[19];
  const float* b1 = (const float*)d_in[20];
  const float* W2 = (const float*)d_in[21];
  const float* b2 = (const float*)d_in[22];
  const float* g2 = (const float*)d_in[23];
  const float* be2 = (const float*)d_in[24];

  float* X = (float*)d_out;  // f32 residual stream lives in d_out

  // ---- workspace layout ----
  char* w = (char*)d_ws;
  const size_t SZ_B = (size_t)NTOK * 256 * 2;
  ushort_t* POSb = (ushort_t*)w;  w += SZ_B;
  ushort_t* Xb = (ushort_t*)w;    w += SZ_B;
  ushort_t* QBb = (ushort_t*)w;   w += SZ_B;
  ushort_t* QAb = (ushort_t*)w;   w += (size_t)NTOK * 384 * 2;
  ushort_t* Vb = (ushort_t*)w;    w += SZ_B;
  ushort_t* SAMPb = (ushort_t*)w; w += SZ_B;
  ushort_t* H1b = (ushort_t*)w;   w += (size_t)NTOK * DFF * 2;
  ushort_t* WT_qa = (ushort_t*)w;  w += (size_t)NLAYERS * 384 * 256 * 2;
  ushort_t* WT_v = (ushort_t*)w;   w += (size_t)NLAYERS * 256 * 256 * 2;
  ushort_t* WT_out = (ushort_t*)w; w += (size_t)NLAYERS * 256 * 256 * 2;
  ushort_t* WT_1 = (ushort_t*)w;   w += (size_t)NLAYERS * 1024 * 256 * 2;
  ushort_t* WT_2 = (ushort_t*)w;   w += (size_t)NLAYERS * 256 * 1024 * 2;
  float* b_qa = (float*)w;         w += (size_t)NLAYERS * 384 * 4;

  // ---- weight prep ----
  transpose_w<<<dim3(8, 8, NLAYERS), dim3(32, 8), 0, stream>>>(W_off, WT_qa, 256, 256, 384 * 256, 0);
  transpose_w<<<dim3(4, 8, NLAYERS), dim3(32, 8), 0, stream>>>(W_aw, WT_qa, 256, 128, 384 * 256, 256);
  pack_bias<<<NLAYERS, 384, 0, stream>>>(b_off, b_aw, b_qa);
  transpose_w<<<dim3(8, 8, NLAYERS), dim3(32, 8), 0, stream>>>(W_v, WT_v, 256, 256, 256 * 256, 0);
  transpose_w<<<dim3(8, 8, NLAYERS), dim3(32, 8), 0, stream>>>(W_out, WT_out, 256, 256, 256 * 256, 0);
  transpose_w<<<dim3(32, 8, NLAYERS), dim3(32, 8), 0, stream>>>(W1, WT_1, 256, 1024, 1024 * 256, 0);
  transpose_w<<<dim3(8, 32, NLAYERS), dim3(32, 8), 0, stream>>>(W2, WT_2, 1024, 256, 256 * 1024, 0);

  static const int LWh[4] = {128, 64, 32, 16};
  static const int LSh[4] = {0, 16384, 20480, 21504};
  for (int l = 0; l < 4; ++l) {
    int hw = LWh[l] * LWh[l];
    dim3 g(hw / 32, DD / 32, BB);
    flatten_level<<<g, dim3(32, 8), 0, stream>>>(src[l], pos[l], lemb, X, Xb, POSb,
                                                 QBb, hw, LSh[l], l);
  }
  write_tail<<<1, 16, 0, stream>>>(X + (size_t)NTOK * DD);

  for (int l = 0; l < NLAYERS; ++l) {
    // fused offsets+logits GEMM (N=384) from q
    gemm_mfma<0, 1><<<dim3(3, MTILES), 256, 0, stream>>>(
        QBb, WT_qa + (size_t)l * 384 * 256, b_qa + l * 384, QAb, 384, 256);
    // values from x
    gemm_mfma<0, 1><<<dim3(2, MTILES), 256, 0, stream>>>(
        Xb, WT_v + (size_t)l * 256 * 256, b_v + l * 256, Vb, 256, 256);
    // fused softmax + meta + gather
    sample_v4<<<NTOK / 2, 256, 0, stream>>>(Vb, QAb, SAMPb);
    // out projection + residual + LN1
    gemm_ln<0><<<LTILES, 256, 0, stream>>>(
        SAMPb, WT_out + (size_t)l * 256 * 256, b_out + l * 256,
        g1 + l * DD, be1 + l * DD, X, Xb, POSb, QBb, 256);
    // FFN
    gemm_mfma<1, 1><<<dim3(8, MTILES), 256, 0, stream>>>(
        Xb, WT_1 + (size_t)l * 1024 * 256, b1 + l * DFF, H1b, 1024, 256);
    gemm_ln<1><<<LTILES, 256, 0, stream>>>(
        H1b, WT_2 + (size_t)l * 256 * 1024, b2 + l * 256,
        g2 + l * DD, be2 + l * DD, X, Xb, POSb, QBb, 1024);
  }
}

// Round 6
// 1919.962 us; speedup vs baseline: 4.6879x; 1.0214x over previous
//
#include <hip/hip_runtime.h>
#include <cstddef>

// ---------------- problem constants ----------------
#define BB 2
#define DD 256
#define NH 8
#define NL 4
#define NP 4
#define DFF 1024
#define NLAYERS 6
#define Q_TOT 21760
#define NTOK (BB * Q_TOT)   // 43520
#define MTILES (NTOK / 128) // 340
#define LTILES (NTOK / 64)  // 680

typedef unsigned short ushort_t;
typedef __attribute__((ext_vector_type(8))) short bh8;
typedef __attribute__((ext_vector_type(4))) float fx4;

__device__ __forceinline__ ushort_t f2b(float x) {
  union { float f; unsigned u; } v; v.f = x;
  unsigned r = v.u + 0x7FFF + ((v.u >> 16) & 1);
  return (ushort_t)(r >> 16);
}
__device__ __forceinline__ float b2f(ushort_t b) {
  union { unsigned u; float f; } v; v.u = ((unsigned)b) << 16; return v.f;
}
__device__ __forceinline__ float b2f_hi(unsigned w) {
  union { unsigned u; float f; } v; v.u = w & 0xFFFF0000u; return v.f;
}
__device__ __forceinline__ float b2f_lo(unsigned w) {
  union { unsigned u; float f; } v; v.u = w << 16; return v.f;
}

__device__ __forceinline__ void gload16(const void* g, void* l) {
  __builtin_amdgcn_global_load_lds(
      (const __attribute__((address_space(1))) unsigned int*)g,
      (__attribute__((address_space(3))) unsigned int*)l, 16, 0, 0);
}

// ---------------- init: flatten + transpose (B,D,H,W) -> (B,Q,D) ----------------
__global__ __launch_bounds__(256) void flatten_level(
    const float* __restrict__ src, const float* __restrict__ pos,
    const float* __restrict__ lemb, float* __restrict__ X,
    ushort_t* __restrict__ Xb, ushort_t* __restrict__ POSb,
    ushort_t* __restrict__ QBb, int HW, int start, int lvl) {
  __shared__ float ts[32][33];
  __shared__ float tp[32][33];
  int p0 = blockIdx.x * 32, d0 = blockIdx.y * 32, b = blockIdx.z;
  const float* sb = src + (size_t)b * DD * HW;
  const float* pb = pos + (size_t)b * DD * HW;
  int px = threadIdx.x;
#pragma unroll
  for (int i = 0; i < 4; ++i) {
    int dl = threadIdx.y + i * 8;
    ts[dl][px] = sb[(size_t)(d0 + dl) * HW + p0 + px];
    tp[dl][px] = pb[(size_t)(d0 + dl) * HW + p0 + px];
  }
  __syncthreads();
  int dx = threadIdx.x;
#pragma unroll
  for (int i = 0; i < 4; ++i) {
    int pl = threadIdx.y + i * 8;
    size_t row = (size_t)b * Q_TOT + start + p0 + pl;
    float s = ts[dx][pl];
    float p = tp[dx][pl] + lemb[lvl * DD + d0 + dx];
    X[row * DD + d0 + dx] = s;
    Xb[row * DD + d0 + dx] = f2b(s);
    POSb[row * DD + d0 + dx] = f2b(p);
    QBb[row * DD + d0 + dx] = f2b(s + p);
  }
}

// ---------------- weight transpose + bf16: W[K][N] -> WT[rowOff+N][K] ----------------
__global__ __launch_bounds__(256) void transpose_w(const float* __restrict__ W,
                                                   ushort_t* __restrict__ WT,
                                                   int K, int N, int outStride,
                                                   int rowOff) {
  __shared__ float t[32][33];
  int n0 = blockIdx.x * 32, k0 = blockIdx.y * 32, l = blockIdx.z;
  const float* in = W + (size_t)l * K * N;
  ushort_t* out = WT + (size_t)l * outStride;
#pragma unroll
  for (int i = 0; i < 4; ++i) {
    int k = threadIdx.y + i * 8;
    t[k][threadIdx.x] = in[(size_t)(k0 + k) * N + n0 + threadIdx.x];
  }
  __syncthreads();
#pragma unroll
  for (int i = 0; i < 4; ++i) {
    int nn = threadIdx.y + i * 8;
    out[(size_t)(rowOff + n0 + nn) * K + k0 + threadIdx.x] = f2b(t[threadIdx.x][nn]);
  }
}

__global__ void pack_bias(const float* __restrict__ b_off,
                          const float* __restrict__ b_aw,
                          float* __restrict__ b_qa) {
  int l = blockIdx.x, i = threadIdx.x;
  b_qa[l * 384 + i] = (i < 256) ? b_off[l * 256 + i] : b_aw[l * 128 + i - 256];
}

// ---------------- bf16 MFMA GEMM (128x128 tile): C = A * Bt^T + bias ----------------
template <int RELU, int OUTBF16>
__global__ __launch_bounds__(256) void gemm_mfma(
    const ushort_t* __restrict__ A, const ushort_t* __restrict__ Bt,
    const float* __restrict__ bias, void* __restrict__ C, int N, int K) {
  __shared__ ushort_t As[128 * 64];
  __shared__ ushort_t Bs[128 * 64];
  int tid = threadIdx.x;
  int m0 = blockIdx.y * 128, n0 = blockIdx.x * 128;
  int wid = tid >> 6, lane = tid & 63;
  int wr = wid >> 1, wc = wid & 1;

  fx4 acc[4][4];
#pragma unroll
  for (int i = 0; i < 4; ++i)
#pragma unroll
    for (int j = 0; j < 4; ++j) acc[i][j] = fx4{0.f, 0.f, 0.f, 0.f};

  const ushort_t* ga = A + (size_t)(m0 + (tid >> 3)) * K + (tid & 7) * 8;
  const ushort_t* gb = Bt + (size_t)(n0 + (tid >> 3)) * K + (tid & 7) * 8;
  int ldsbase = wid * 1024;

  for (int k0 = 0; k0 < K; k0 += 64) {
#pragma unroll
    for (int it = 0; it < 4; ++it) {
      gload16(ga + (size_t)(it * 32) * K + k0, (char*)As + ldsbase + it * 4096);
      gload16(gb + (size_t)(it * 32) * K + k0, (char*)Bs + ldsbase + it * 4096);
    }
    __syncthreads();
#pragma unroll
    for (int kk = 0; kk < 2; ++kk) {
      bh8 af[4], bf[4];
      int cb = kk * 64 + (lane >> 4) * 16;
      int ra = wr * 64 + (lane & 15);
      int rb = wc * 64 + (lane & 15);
#pragma unroll
      for (int i = 0; i < 4; ++i)
        af[i] = *(const bh8*)((const char*)As + (ra + i * 16) * 128 + cb);
#pragma unroll
      for (int i = 0; i < 4; ++i)
        bf[i] = *(const bh8*)((const char*)Bs + (rb + i * 16) * 128 + cb);
#pragma unroll
      for (int i = 0; i < 4; ++i)
#pragma unroll
        for (int j = 0; j < 4; ++j)
          acc[i][j] = __builtin_amdgcn_mfma_f32_16x16x32_bf16(af[i], bf[j], acc[i][j], 0, 0, 0);
    }
    __syncthreads();
  }

  int crow = m0 + wr * 64 + (lane >> 4) * 4;
  int ccol = n0 + wc * 64 + (lane & 15);
#pragma unroll
  for (int j = 0; j < 4; ++j) {
    float bv = bias[ccol + j * 16];
#pragma unroll
    for (int i = 0; i < 4; ++i) {
#pragma unroll
      for (int r = 0; r < 4; ++r) {
        float v = acc[i][j][r] + bv;
        if (RELU) v = fmaxf(v, 0.f);
        size_t idx = (size_t)(crow + i * 16 + r) * N + ccol + j * 16;
        if (OUTBF16) ((ushort_t*)C)[idx] = f2b(v);
        else ((float*)C)[idx] = v;
      }
    }
  }
}

// ---- bf16 MFMA GEMM (64x256, BK=32, XOR-swizzled, DOUBLE-BUFFERED) + res + LN ----
// 2-phase pipeline: stage(t+1) issued before compute(t); single barrier per tile
// (the __syncthreads vmcnt(0) drain lands AFTER compute, so HBM latency hides
// under ds_read+MFMA of the current tile instead of being serially exposed).
template <int QOUT>
__global__ __launch_bounds__(256) void gemm_ln(
    const ushort_t* __restrict__ A, const ushort_t* __restrict__ Bt,
    const float* __restrict__ bias, const float* __restrict__ gamma,
    const float* __restrict__ beta, float* __restrict__ Xf,
    ushort_t* __restrict__ Xb, const ushort_t* __restrict__ POSb,
    ushort_t* __restrict__ QBb, int K) {
  __shared__ ushort_t As[2][64 * 32];
  __shared__ ushort_t Bs[2][256 * 32];
  __shared__ float red[2][2][64];
  int tid = threadIdx.x;
  int m0 = blockIdx.x * 64;
  int wid = tid >> 6, lane = tid & 63;
  int wr = wid >> 1, wc = wid & 1;  // wave: rows wr*32..+32, cols wc*128..+128

  fx4 acc[2][8];
#pragma unroll
  for (int i = 0; i < 2; ++i)
#pragma unroll
    for (int j = 0; j < 8; ++j) acc[i][j] = fx4{0.f, 0.f, 0.f, 0.f};

  // staging: thread t -> LDS row t>>2 (64B rows), slot t&3; global slot
  // pre-swizzled by ((row>>1)&3) = (t>>3)&3.
  int srow = tid >> 2;
  int sslot = (tid & 3) ^ ((tid >> 3) & 3);
  const ushort_t* ga = A + (size_t)(m0 + srow) * K + sslot * 8;
  const ushort_t* gb = Bt + (size_t)srow * K + sslot * 8;
  int ldsoff = wid * 1024;

  // read-side swizzled column byte offset (lane-only)
  int cbyte = (((lane >> 4) ^ ((lane >> 1) & 3)) << 4);
  int ra = wr * 32 + (lane & 15);
  int rb = wc * 128 + (lane & 15);

  // prologue: stage tile 0 into buffer 0
  gload16(ga, (char*)As[0] + ldsoff);
#pragma unroll
  for (int it = 0; it < 4; ++it)
    gload16(gb + (size_t)(it * 64) * K, (char*)Bs[0] + it * 4096 + ldsoff);
  __syncthreads();

  int nt = K >> 5;
  int cur = 0;
  for (int t = 0; t < nt; ++t) {
    if (t + 1 < nt) {
      int k1 = (t + 1) << 5;
      gload16(ga + k1, (char*)As[cur ^ 1] + ldsoff);
#pragma unroll
      for (int it = 0; it < 4; ++it)
        gload16(gb + (size_t)(it * 64) * K + k1, (char*)Bs[cur ^ 1] + it * 4096 + ldsoff);
    }
    bh8 af[2], bf[8];
#pragma unroll
    for (int i = 0; i < 2; ++i)
      af[i] = *(const bh8*)((const char*)As[cur] + (ra + i * 16) * 64 + cbyte);
#pragma unroll
    for (int j = 0; j < 8; ++j)
      bf[j] = *(const bh8*)((const char*)Bs[cur] + (rb + j * 16) * 64 + cbyte);
#pragma unroll
    for (int i = 0; i < 2; ++i)
#pragma unroll
      for (int j = 0; j < 8; ++j)
        acc[i][j] = __builtin_amdgcn_mfma_f32_16x16x32_bf16(af[i], bf[j], acc[i][j], 0, 0, 0);
    __syncthreads();
    cur ^= 1;
  }

  int lg = lane >> 4, lc = lane & 15;
  float bv[8], gv[8], bev[8];
#pragma unroll
  for (int j = 0; j < 8; ++j) {
    int col = wc * 128 + j * 16 + lc;
    bv[j] = bias[col];
    gv[j] = gamma[col];
    bev[j] = beta[col];
  }
  // pass 1: v = acc + bias + residual; per-row sum/sumsq
#pragma unroll
  for (int i = 0; i < 2; ++i) {
#pragma unroll
    for (int r = 0; r < 4; ++r) {
      int rloc = wr * 32 + i * 16 + lg * 4 + r;
      const float* xr = Xf + (size_t)(m0 + rloc) * DD + wc * 128 + lc;
      float s = 0.f, s2 = 0.f;
#pragma unroll
      for (int j = 0; j < 8; ++j) {
        float v = acc[i][j][r] + bv[j] + xr[j * 16];
        acc[i][j][r] = v;
        s += v;
        s2 += v * v;
      }
#pragma unroll
      for (int o = 1; o < 16; o <<= 1) {
        s += __shfl_xor(s, o);
        s2 += __shfl_xor(s2, o);
      }
      if (lc == 0) {
        red[wc][0][rloc] = s;
        red[wc][1][rloc] = s2;
      }
    }
  }
  __syncthreads();
  // pass 2: normalize + write f32 / bf16 / optional q = bf16(y + pos)
#pragma unroll
  for (int i = 0; i < 2; ++i) {
#pragma unroll
    for (int r = 0; r < 4; ++r) {
      int rloc = wr * 32 + i * 16 + lg * 4 + r;
      float s = red[0][0][rloc] + red[1][0][rloc];
      float s2 = red[0][1][rloc] + red[1][1][rloc];
      float mmean = s * (1.f / 256.f);
      float var = s2 * (1.f / 256.f) - mmean * mmean;
      float inv = rsqrtf(var + 1e-5f);
      size_t rowb = (size_t)(m0 + rloc) * DD + wc * 128 + lc;
#pragma unroll
      for (int j = 0; j < 8; ++j) {
        float y = (acc[i][j][r] - mmean) * inv * gv[j] + bev[j];
        Xf[rowb + j * 16] = y;
        Xb[rowb + j * 16] = f2b(y);
        if (QOUT) QBb[rowb + j * 16] = f2b(y + b2f(POSb[rowb + j * 16]));
      }
    }
  }
}

// ---------------- fused softmax + meta + gather sampler ----------------
__global__ __launch_bounds__(256) void sample_v4(const ushort_t* __restrict__ Vb,
                                                 const ushort_t* __restrict__ QA,
                                                 ushort_t* __restrict__ SAMPb) {
  int nb = NTOK / 2;
  int bid = blockIdx.x;
  int newb = (bid & 7) * (nb >> 3) + (bid >> 3);  // XCD-chunked swizzle
  int t = newb * 2 + (threadIdx.x >> 7);
  int h = (threadIdx.x >> 4) & 7;
  int p = threadIdx.x & 15;

  int b = (t >= Q_TOT) ? 1 : 0;
  int qi = t - b * Q_TOT;
  int lwq = (qi < 16384) ? 7 : (qi < 20480) ? 6 : (qi < 21504) ? 5 : 4;
  int stq = (qi < 16384) ? 0 : (qi < 20480) ? 16384 : (qi < 21504) ? 20480 : 21504;
  int wt = 1 << lwq;
  int pidx = qi - stq;
  int iy = pidx >> lwq, ix = pidx & (wt - 1);
  float refx = (ix + 0.5f) / (float)wt;
  float refy = (iy + 0.5f) / (float)wt;

  // softmax over the 16 points (one logit per lane)
  float lgt = b2f(QA[(size_t)t * 384 + 256 + h * 16 + p]);
  float mxv = lgt;
#pragma unroll
  for (int o = 1; o < 16; o <<= 1) mxv = fmaxf(mxv, __shfl_xor(mxv, o, 16));
  float e = __expf(lgt - mxv);
  float sum = e;
#pragma unroll
  for (int o = 1; o < 16; o <<= 1) sum += __shfl_xor(sum, o, 16);
  float a = e / sum;

  // bilinear meta for point p = (level l, point pt)
  int l = p >> 2, pt = p & 3;
  int wl = 128 >> l;
  int LSl = (l > 0 ? 16384 : 0) + (l > 1 ? 4096 : 0) + (l > 2 ? 1024 : 0);
  float fw = (float)wl;
  unsigned ow = *(const unsigned*)(QA + (size_t)t * 384 + h * 32 + l * 8 + pt * 2);
  float ox = b2f_lo(ow), oy = b2f_hi(ow);
  float Xc = refx * fw + ox - 0.5f;
  float Yc = refy * fw + oy - 0.5f;
  float xf = floorf(Xc), yf = floorf(Yc);
  float wx = Xc - xf, wy = Yc - yf;
  int x0 = (int)xf, y0 = (int)yf;
  int x1 = x0 + 1, y1 = y0 + 1;
  float ok_x0 = (x0 >= 0 && x0 < wl) ? 1.f : 0.f;
  float ok_x1 = (x1 >= 0 && x1 < wl) ? 1.f : 0.f;
  float ok_y0 = (y0 >= 0 && y0 < wl) ? 1.f : 0.f;
  float ok_y1 = (y1 >= 0 && y1 < wl) ? 1.f : 0.f;
  int xc0 = min(max(x0, 0), wl - 1), xc1 = min(max(x1, 0), wl - 1);
  int yc0 = min(max(y0, 0), wl - 1), yc1 = min(max(y1, 0), wl - 1);
  float w00 = (1.f - wx) * (1.f - wy) * a * ok_x0 * ok_y0;
  float w10 = wx * (1.f - wy) * a * ok_x1 * ok_y0;
  float w01 = (1.f - wx) * wy * a * ok_x0 * ok_y1;
  float w11 = wx * wy * a * ok_x1 * ok_y1;
  int metaBase = ((b * Q_TOT + LSl + yc0 * wl + xc0) << 8) + h * 32;
  int metaDxy = (int)(((unsigned)((xc1 - xc0) << 8)) |
                      (((unsigned)((yc1 - yc0) * wl) << 8) << 16));
  int metaZ = (int)(((unsigned)f2b(w00) << 16) | f2b(w10));
  int metaW = (int)(((unsigned)f2b(w01) << 16) | f2b(w11));

  int c2 = p * 2;  // this lane's channel pair within the head
  float acc0 = 0.f, acc1 = 0.f;
#pragma unroll
  for (int pp = 0; pp < 16; ++pp) {
    int m0v = __shfl(metaBase, pp, 16);
    int m1v = __shfl(metaDxy, pp, 16);
    int mzv = __shfl(metaZ, pp, 16);
    int mwv = __shfl(metaW, pp, 16);
    unsigned dxy = (unsigned)m1v;
    int base = m0v + c2;
    int dx = (int)(dxy & 0xffffu);
    int dy = (int)(dxy >> 16);
    unsigned v00 = *(const unsigned*)(Vb + base);
    unsigned v10 = *(const unsigned*)(Vb + base + dx);
    unsigned v01 = *(const unsigned*)(Vb + base + dy);
    unsigned v11 = *(const unsigned*)(Vb + base + dy + dx);
    unsigned wz = (unsigned)mzv, ww = (unsigned)mwv;
    float f00 = b2f_hi(wz), f10 = b2f_lo(wz);
    float f01 = b2f_hi(ww), f11 = b2f_lo(ww);
    acc0 = fmaf(f00, b2f_lo(v00), acc0);
    acc1 = fmaf(f00, b2f_hi(v00), acc1);
    acc0 = fmaf(f10, b2f_lo(v10), acc0);
    acc1 = fmaf(f10, b2f_hi(v10), acc1);
    acc0 = fmaf(f01, b2f_lo(v01), acc0);
    acc1 = fmaf(f01, b2f_hi(v01), acc1);
    acc0 = fmaf(f11, b2f_lo(v11), acc0);
    acc1 = fmaf(f11, b2f_hi(v11), acc1);
  }
  unsigned outw = (unsigned)f2b(acc0) | ((unsigned)f2b(acc1) << 16);
  *(unsigned*)(SAMPb + (size_t)t * 256 + h * 32 + c2) = outw;
}

// ---------------- tail: spatial_shapes + level_start_index (as f32) ----------------
__global__ void write_tail(float* __restrict__ t) {
  int i = threadIdx.x;
  float v = 0.f;
  switch (i) {
    case 0: v = 128.f; break;
    case 1: v = 128.f; break;
    case 2: v = 64.f; break;
    case 3: v = 64.f; break;
    case 4: v = 32.f; break;
    case 5: v = 32.f; break;
    case 6: v = 16.f; break;
    case 7: v = 16.f; break;
    case 8: v = 0.f; break;
    case 9: v = 16384.f; break;
    case 10: v = 20480.f; break;
    case 11: v = 21504.f; break;
    default: return;
  }
  t[i] = v;
}

// ---------------- launch ----------------
extern "C" void kernel_launch(void* const* d_in, const int* in_sizes, int n_in,
                              void* d_out, int out_size, void* d_ws, size_t ws_size,
                              hipStream_t stream) {
  const float* src[4] = {(const float*)d_in[0], (const float*)d_in[2],
                         (const float*)d_in[4], (const float*)d_in[6]};
  const float* pos[4] = {(const float*)d_in[1], (const float*)d_in[3],
                         (const float*)d_in[5], (const float*)d_in[7]};
  const float* lemb = (const float*)d_in[8];
  const float* W_off = (const float*)d_in[9];
  const float* b_off = (const float*)d_in[10];
  const float* W_aw = (const float*)d_in[11];
  const float* b_aw = (const float*)d_in[12];
  const float* W_v = (const float*)d_in[13];
  const float* b_v = (const float*)d_in[14];
  const float* W_out = (const float*)d_in[15];
  const float* b_out = (const float*)d_in[16];
  const float* g1 = (const float*)d_in[17];
  const float* be1 = (const float*)d_in[18];
  const float* W1 = (const float*)d_in[19];
  const float* b1 = (const float*)d_in[20];
  const float* W2 = (const float*)d_in[21];
  const float* b2 = (const float*)d_in[22];
  const float* g2 = (const float*)d_in[23];
  const float* be2 = (const float*)d_in[24];

  float* X = (float*)d_out;  // f32 residual stream lives in d_out

  // ---- workspace layout ----
  char* w = (char*)d_ws;
  const size_t SZ_B = (size_t)NTOK * 256 * 2;
  ushort_t* POSb = (ushort_t*)w;  w += SZ_B;
  ushort_t* Xb = (ushort_t*)w;    w += SZ_B;
  ushort_t* QBb = (ushort_t*)w;   w += SZ_B;
  ushort_t* QAb = (ushort_t*)w;   w += (size_t)NTOK * 384 * 2;
  ushort_t* Vb = (ushort_t*)w;    w += SZ_B;
  ushort_t* SAMPb = (ushort_t*)w; w += SZ_B;
  ushort_t* H1b = (ushort_t*)w;   w += (size_t)NTOK * DFF * 2;
  ushort_t* WT_qa = (ushort_t*)w;  w += (size_t)NLAYERS * 384 * 256 * 2;
  ushort_t* WT_v = (ushort_t*)w;   w += (size_t)NLAYERS * 256 * 256 * 2;
  ushort_t* WT_out = (ushort_t*)w; w += (size_t)NLAYERS * 256 * 256 * 2;
  ushort_t* WT_1 = (ushort_t*)w;   w += (size_t)NLAYERS * 1024 * 256 * 2;
  ushort_t* WT_2 = (ushort_t*)w;   w += (size_t)NLAYERS * 256 * 1024 * 2;
  float* b_qa = (float*)w;         w += (size_t)NLAYERS * 384 * 4;

  // ---- weight prep ----
  transpose_w<<<dim3(8, 8, NLAYERS), dim3(32, 8), 0, stream>>>(W_off, WT_qa, 256, 256, 384 * 256, 0);
  transpose_w<<<dim3(4, 8, NLAYERS), dim3(32, 8), 0, stream>>>(W_aw, WT_qa, 256, 128, 384 * 256, 256);
  pack_bias<<<NLAYERS, 384, 0, stream>>>(b_off, b_aw, b_qa);
  transpose_w<<<dim3(8, 8, NLAYERS), dim3(32, 8), 0, stream>>>(W_v, WT_v, 256, 256, 256 * 256, 0);
  transpose_w<<<dim3(8, 8, NLAYERS), dim3(32, 8), 0, stream>>>(W_out, WT_out, 256, 256, 256 * 256, 0);
  transpose_w<<<dim3(32, 8, NLAYERS), dim3(32, 8), 0, stream>>>(W1, WT_1, 256, 1024, 1024 * 256, 0);
  transpose_w<<<dim3(8, 32, NLAYERS), dim3(32, 8), 0, stream>>>(W2, WT_2, 1024, 256, 256 * 1024, 0);

  static const int LWh[4] = {128, 64, 32, 16};
  static const int LSh[4] = {0, 16384, 20480, 21504};
  for (int l = 0; l < 4; ++l) {
    int hw = LWh[l] * LWh[l];
    dim3 g(hw / 32, DD / 32, BB);
    flatten_level<<<g, dim3(32, 8), 0, stream>>>(src[l], pos[l], lemb, X, Xb, POSb,
                                                 QBb, hw, LSh[l], l);
  }
  write_tail<<<1, 16, 0, stream>>>(X + (size_t)NTOK * DD);

  for (int l = 0; l < NLAYERS; ++l) {
    // fused offsets+logits GEMM (N=384) from q
    gemm_mfma<0, 1><<<dim3(3, MTILES), 256, 0, stream>>>(
        QBb, WT_qa + (size_t)l * 384 * 256, b_qa + l * 384, QAb, 384, 256);
    // values from x
    gemm_mfma<0, 1><<<dim3(2, MTILES), 256, 0, stream>>>(
        Xb, WT_v + (size_t)l * 256 * 256, b_v + l * 256, Vb, 256, 256);
    // fused softmax + meta + gather
    sample_v4<<<NTOK / 2, 256, 0, stream>>>(Vb, QAb, SAMPb);
    // out projection + residual + LN1
    gemm_ln<0><<<LTILES, 256, 0, stream>>>(
        SAMPb, WT_out + (size_t)l * 256 * 256, b_out + l * 256,
        g1 + l * DD, be1 + l * DD, X, Xb, POSb, QBb, 256);
    // FFN
    gemm_mfma<1, 1><<<dim3(8, MTILES), 256, 0, stream>>>(
        Xb, WT_1 + (size_t)l * 1024 * 256, b1 + l * DFF, H1b, 1024, 256);
    gemm_ln<1><<<LTILES, 256, 0, stream>>>(
        H1b, WT_2 + (size_t)l * 256 * 1024, b2 + l * 256,
        g2 + l * DD, be2 + l * DD, X, Xb, POSb, QBb, 1024);
  }
}